// Round 10
// baseline (620.956 us; speedup 1.0000x reference)
//
#include <hip/hip_runtime.h>

#define DI __device__ __forceinline__

typedef __attribute__((ext_vector_type(8))) short bf16x8;
typedef __attribute__((ext_vector_type(4))) short s16x4;
typedef __attribute__((ext_vector_type(4))) float f32x4;

DI short f2bf(float f) {
  unsigned u = __builtin_bit_cast(unsigned, f);
  u += 0x7FFFu + ((u >> 16) & 1u);
  return (short)(u >> 16);
}

#define WAITVM(N) asm volatile("s_waitcnt vmcnt(" #N ")" ::: "memory")
#define AS1 __attribute__((address_space(1)))
#define AS3 __attribute__((address_space(3)))

// Within-64 column permutation used for packed epilogues:
//   position p holds true column c:  p = (c&~63) + (c&15)*4 + ((c>>4)&3)
// Applied consistently to {P positions, vbuf j} (PV contraction) and
// {Wo cols, oT cols} (output-GEMM contraction) -> cancels algebraically.
//
// R8: vbuf tiled [jb=72][cb=32][16][32] (1KB-contiguous loads).
// R9: all bf16 [n][512] intermediates K-chunk-tiled:
//   off(n,k) = (n>>7)*65536 + (k>>5)*4096 + (n&127)*32 + (k&31)
// R10: S+PV FUSED — P lives in LDS only (no HBM round-trip).

// ---------------- prep: weights -> bf16 (+ transposed Wk/Wq for G) ----------
__global__ __launch_bounds__(256) void prep_k(
    const float* __restrict__ wq, const float* __restrict__ wk,
    const float* __restrict__ wv, const float* __restrict__ wo,
    short* __restrict__ Wv, short* __restrict__ Wo,
    short* __restrict__ WkT, short* __restrict__ WqT) {
  const int i = blockIdx.x * 256 + threadIdx.x;  // 0..262143
  const float sc = 0.04419417382415922f;         // 1/sqrt(512)
  const int o = i >> 9, c = i & 511;
  Wv[(o >> 7) * 65536 + (c >> 5) * 4096 + (o & 127) * 32 + (c & 31)] = f2bf(wv[i]);
  const int cp = (c & ~63) | ((c & 15) << 2) | ((c >> 4) & 3);
  Wo[(o >> 7) * 65536 + (cp >> 5) * 4096 + (o & 127) * 32 + (cp & 31)] = f2bf(wo[i]);
  const int tr = c * 512 + o;
  WkT[tr] = f2bf(wk[i] * sc);   // scale folded into Wk side
  WqT[tr] = f2bf(wq[i]);
}

// ---------------- g0[c'] = s * sum_o wk[o][c'] * bq[o] ----------------------
__global__ __launch_bounds__(256) void g0_k(const float* __restrict__ wk,
                                            const float* __restrict__ bq,
                                            float* __restrict__ g0) {
  const int c = blockIdx.x * 256 + threadIdx.x;  // 0..511
  float acc = 0.f;
#pragma unroll 8
  for (int o = 0; o < 512; ++o) acc += wk[o * 512 + c] * bq[o];
  g0[c] = acc * 0.04419417382415922f;
}

// ---------------- GroupNorm pass 1: per (b,g) mean/rstd ---------------------
__global__ __launch_bounds__(256) void gn_stats(const float* __restrict__ x,
                                                float2* __restrict__ stats) {
  const int bg = blockIdx.x;
  const float4* xg = (const float4*)(x + (size_t)bg * 36864);
  float s = 0.f, q = 0.f;
  for (int i = threadIdx.x; i < 9216; i += 256) {
    float4 v = xg[i];
    s += v.x + v.y + v.z + v.w;
    q += v.x * v.x + v.y * v.y + v.z * v.z + v.w * v.w;
  }
#pragma unroll
  for (int d = 1; d < 64; d <<= 1) { s += __shfl_xor(s, d); q += __shfl_xor(q, d); }
  __shared__ float rs[4], rq[4];
  const int w = threadIdx.x >> 6;
  if ((threadIdx.x & 63) == 0) { rs[w] = s; rq[w] = q; }
  __syncthreads();
  if (threadIdx.x == 0) {
    float S = rs[0] + rs[1] + rs[2] + rs[3];
    float Q = rq[0] + rq[1] + rq[2] + rq[3];
    float mean = S * (1.f / 36864.f);
    float var  = Q * (1.f / 36864.f) - mean * mean;
    float2 o; o.x = mean; o.y = rsqrtf(var + 1e-5f);
    stats[bg] = o;
  }
}

// ---------------- GroupNorm pass 2: normalize + transpose -> yT bf16 --------
__global__ __launch_bounds__(256) void gn_norm_t(
    const float* __restrict__ x, const float2* __restrict__ stats,
    const float* __restrict__ gamma, const float* __restrict__ beta,
    short* __restrict__ yT) {
  __shared__ float ts[64][68];
  const int n0 = blockIdx.x * 64, c0 = blockIdx.y * 64, b = blockIdx.z;
  const int t = threadIdx.x;
  {
    const int cw = t >> 4;
    const int n4 = (t & 15) * 4;
    const float* xb = x + ((size_t)b * 512 + c0) * 2304 + n0;
#pragma unroll
    for (int r4 = 0; r4 < 4; ++r4) {
      const int c = cw + r4 * 16;
      float4 v = *(const float4*)(xb + (size_t)c * 2304 + n4);
      *(float4*)&ts[c][n4] = v;
    }
  }
  __syncthreads();
  {
    const int c4 = t & 15;
    const int nw = t >> 4;
    const int cg = c0 + c4 * 4;
    const float2 ms = stats[b * 32 + (cg >> 4)];
    const float4 gm = *(const float4*)(gamma + cg);
    const float4 bt = *(const float4*)(beta + cg);
    const float a0 = ms.y * gm.x, a1 = ms.y * gm.y, a2 = ms.y * gm.z, a3 = ms.y * gm.w;
    const float d0 = bt.x - ms.x * a0, d1 = bt.y - ms.x * a1,
                d2 = bt.z - ms.x * a2, d3 = bt.w - ms.x * a3;
#pragma unroll
    for (int it = 0; it < 4; ++it) {
      const int no = nw + it * 16;
      const int n = n0 + no;
      const float v0 = ts[c4 * 4 + 0][no], v1 = ts[c4 * 4 + 1][no];
      const float v2 = ts[c4 * 4 + 2][no], v3 = ts[c4 * 4 + 3][no];
      s16x4 o = { f2bf(v0 * a0 + d0), f2bf(v1 * a1 + d1),
                  f2bf(v2 * a2 + d2), f2bf(v3 * a3 + d3) };
      *(s16x4*)(yT + (size_t)b * 2304 * 512 + (n >> 7) * 65536 +
                (cg >> 5) * 4096 + (n & 127) * 32 + (cg & 31)) = o;
    }
  }
}

// ---------------- Generic bf16 MFMA GEMM (depth-3 ring) ---------------------
template <int EPI, bool BIASROW, bool AT, bool BT, bool DT, int LDA, int LDB,
          int KSTEPS>
__global__ __launch_bounds__(256) void gemm_k(
    const short* __restrict__ A, size_t sA,
    const short* __restrict__ Bt, size_t sB,
    void* __restrict__ Dp, size_t sD,
    const float* __restrict__ bias, const float* __restrict__ resid,
    int N, int tilesM, int boff) {
  __shared__ short As[3][128 * 32];
  __shared__ short Bs[3][128 * 32];
  const int ba = blockIdx.y, bb = blockIdx.y + boff;
  int bx = blockIdx.x;
  bx = (bx & 7) * (int)(gridDim.x >> 3) + (bx >> 3);
  const int tm = bx % tilesM, tn = bx / tilesM;
  const int row0 = tm * 128, col0 = tn * 128;
  const int tid = threadIdx.x, lane = tid & 63, w = tid >> 6;
  const int lr = lane & 15, lg = lane >> 4;
  const short* Ab = A + (size_t)ba * sA;
  const short* Bb = Bt + (size_t)bb * sB;
  f32x4 acc[4][4];
  const f32x4 zero = {0.f, 0.f, 0.f, 0.f};
#pragma unroll
  for (int i = 0; i < 4; ++i)
#pragma unroll
    for (int j = 0; j < 4; ++j) acc[i][j] = zero;
  const int wrow = (w & 1) * 64, wcol = (w >> 1) * 64;
  const int sw = (lg ^ ((lr >> 1) & 3)) * 8;

#define GK_STAGE(KS, BUF)                                                      \
  {                                                                            \
    _Pragma("unroll")                                                          \
    for (int j = 0; j < 2; ++j) {                                              \
      const int g = (w * 2 + j) * 64 + lane;                                   \
      const int sub8 = ((g & 3) ^ ((g >> 3) & 3)) * 8;                         \
      const short* ga = AT ? (Ab + (size_t)row0 * 512 + (KS) * 4096 +          \
                              (g >> 2) * 32 + sub8)                            \
                           : (Ab + (size_t)(row0 + (g >> 2)) * LDA +           \
                              (KS) * 32 + sub8);                               \
      const short* gb = BT ? (Bb + (size_t)col0 * 512 + (KS) * 4096 +          \
                              (g >> 2) * 32 + sub8)                            \
                           : (Bb + (size_t)(col0 + (g >> 2)) * LDB +           \
                              (KS) * 32 + sub8);                               \
      __builtin_amdgcn_global_load_lds(                                        \
          (AS1 void*)ga, (AS3 void*)&As[BUF][(w * 2 + j) * 512], 16, 0, 0);    \
      __builtin_amdgcn_global_load_lds(                                        \
          (AS1 void*)gb, (AS3 void*)&Bs[BUF][(w * 2 + j) * 512], 16, 0, 0);    \
    }                                                                          \
  }

  GK_STAGE(0, 0);
  GK_STAGE(1, 1);
  GK_STAGE(2, 2);
  int cur = 0;
  for (int ks = 0; ks < KSTEPS; ++ks) {
    if (ks + 2 < KSTEPS)      WAITVM(8);
    else if (ks + 1 < KSTEPS) WAITVM(4);
    else                      WAITVM(0);
    __builtin_amdgcn_sched_barrier(0);
    __builtin_amdgcn_s_barrier();
    bf16x8 af[4], bfr[4];
#pragma unroll
    for (int mi = 0; mi < 4; ++mi)
      af[mi] = *(const bf16x8*)&As[cur][(wrow + mi * 16 + lr) * 32 + sw];
#pragma unroll
    for (int nj = 0; nj < 4; ++nj)
      bfr[nj] = *(const bf16x8*)&Bs[cur][(wcol + nj * 16 + lr) * 32 + sw];
    __builtin_amdgcn_s_setprio(1);
#pragma unroll
    for (int mi = 0; mi < 4; ++mi)
#pragma unroll
      for (int nj = 0; nj < 4; ++nj)
        acc[mi][nj] = __builtin_amdgcn_mfma_f32_16x16x32_bf16(af[mi], bfr[nj], acc[mi][nj], 0, 0, 0);
    __builtin_amdgcn_s_setprio(0);
    __builtin_amdgcn_s_barrier();
    if (ks + 3 < KSTEPS) { GK_STAGE(ks + 3, cur) }
    cur = (cur == 2) ? 0 : cur + 1;
  }
#undef GK_STAGE

  const size_t bD = (size_t)bb * sD;
  if (EPI == 3) {
    const int colpos = col0 + wcol + lr * 4;
    const int jb = colpos >> 5, j5 = colpos & 31;
#pragma unroll
    for (int mi = 0; mi < 4; ++mi) {
#pragma unroll
      for (int r = 0; r < 4; ++r) {
        const int row = row0 + wrow + mi * 16 + lg * 4 + r;
        const float bv = bias[row];
        const int off = (jb * 32 + (row >> 4)) * 512 + ((row & 15) << 5) + j5;
        s16x4 o = { f2bf(acc[mi][0][r] + bv), f2bf(acc[mi][1][r] + bv),
                    f2bf(acc[mi][2][r] + bv), f2bf(acc[mi][3][r] + bv) };
        *(s16x4*)&((short*)Dp)[bD + off] = o;
      }
    }
  } else {
#pragma unroll
    for (int mi = 0; mi < 4; ++mi) {
#pragma unroll
      for (int nj = 0; nj < 4; ++nj) {
        const int col = col0 + wcol + nj * 16 + lr;
#pragma unroll
        for (int r = 0; r < 4; ++r) {
          const int row = row0 + wrow + mi * 16 + lg * 4 + r;
          float v = acc[mi][nj][r];
          if (EPI != 2) v += (BIASROW ? bias[row] : bias[col]);
          if (EPI == 1) {
            const size_t idx = bD + (size_t)row * N + col;
            ((float*)Dp)[idx] = v + resid[idx];
          } else {
            const size_t idx = bD + (DT
                ? (size_t)((row >> 7) * 65536 + (col >> 5) * 4096 +
                           (row & 127) * 32 + (col & 31))
                : (size_t)row * N + col);
            ((short*)Dp)[idx] = f2bf(v);
          }
        }
      }
    }
  }
}

// ---------------- FUSED S+PV: flash-style, P never leaves LDS ---------------
// Per block (48-row i-tile, batch): for each of 18 j-tiles:
//   S-phase: S48x128 = z(48rows) @ yT(jt)^T, 16 K-steps, depth-3 ring with a
//     GLOBAL stage counter (ring never drains across j-tiles; counted vmcnt).
//   exp:    P = exp(S-30) -> swizzled LDS (PERMUTED positions matching vbuf's
//           j-permutation); row-sums via shfl + LDS atomicAdd into l_run.
//   PV:     acc_pv += P_lds @ V (tiled vbuf, double-banked register loads).
// Final: acc_pv / l_run -> oT (K-chunk-tiled, c-permuted cols; in-place over
// z is safe: block reads only its own 48 z-rows, all drained by vmcnt(0)).
__global__ __launch_bounds__(512, 4) void gemm_spv(
    const short* __restrict__ z, const short* __restrict__ yT,
    const short* __restrict__ vsrc, short* __restrict__ Dp) {
  __shared__ short Zs[3][48 * 32];    // 3 x 3 KB
  __shared__ short Ys[3][128 * 32];   // 3 x 8 KB
  __shared__ short Pl[48 * 128];      // 12 KB, XOR-swizzled 16B chunks
  __shared__ float l_run[48];
  const int id = blockIdx.y * 48 + blockIdx.x;   // 768 blocks = 3/CU
  const int xcd = id & 7, r8 = id >> 3;          // r8 in [0,96)
  const int b = xcd * 2 + (r8 >= 48 ? 1 : 0);    // 2 batches per XCD
  const int tm = (r8 >= 48) ? r8 - 48 : r8;
  const int row0 = tm * 48;
  const int tid = threadIdx.x, lane = tid & 63, w = tid >> 6;  // 8 waves
  const int lr = lane & 15, lg = lane >> 4;
  const short* Zb = z + (size_t)b * 2304 * 512;
  const short* Yb = yT + (size_t)b * 2304 * 512;
  const short* Vb = vsrc + (size_t)b * 512 * 2304;
  const short* Vp0 = Vb + (w * 4 + 0) * 512 + lr * 32 + lg * 8;
  const short* Vp1 = Vb + (w * 4 + 1) * 512 + lr * 32 + lg * 8;
  const short* Vp2 = Vb + (w * 4 + 2) * 512 + lr * 32 + lg * 8;
  const short* Vp3 = Vb + (w * 4 + 3) * 512 + lr * 32 + lg * 8;
  f32x4 accp[3][4];
  const f32x4 zero = {0.f, 0.f, 0.f, 0.f};
#pragma unroll
  for (int i = 0; i < 3; ++i)
#pragma unroll
    for (int j = 0; j < 4; ++j) accp[i][j] = zero;
  const int sw = (lg ^ ((lr >> 1) & 3)) * 8;
  if (tid < 48) l_run[tid] = 0.f;      // first ks-barrier syncs before use

  // stage(gs): gs = jt*16+ks. Every thread stages one Y chunk (512 total);
  // waves 0-2 also one Z chunk (192). Loads/stage: w<3: 2 (Y,Z), else 1.
#define SPV_STG(GS, BUF)                                                       \
  {                                                                            \
    const int ks_ = (GS) & 15, jt_ = (GS) >> 4;                                \
    const int sub8 = ((tid & 3) ^ ((tid >> 3) & 3)) * 8;                       \
    const short* gy = Yb + (size_t)jt_ * 65536 + ks_ * 4096 +                  \
                      (tid >> 2) * 32 + sub8;                                  \
    __builtin_amdgcn_global_load_lds(                                          \
        (AS1 void*)gy, (AS3 void*)&Ys[BUF][w * 512], 16, 0, 0);                \
    if (w < 3) {                                                               \
      const int n = row0 + (tid >> 2);                                         \
      const short* gz = Zb + (size_t)(n >> 7) * 65536 + ks_ * 4096 +           \
                        (n & 127) * 32 + sub8;                                 \
      __builtin_amdgcn_global_load_lds(                                        \
          (AS1 void*)gz, (AS3 void*)&Zs[BUF][w * 512], 16, 0, 0);              \
    }                                                                          \
  }

#define SPV_VL(BANK, JB)                                                       \
  {                                                                            \
    BANK[0] = *(const bf16x8*)(Vp0 + (size_t)(JB) * 16384);                    \
    BANK[1] = *(const bf16x8*)(Vp1 + (size_t)(JB) * 16384);                    \
    BANK[2] = *(const bf16x8*)(Vp2 + (size_t)(JB) * 16384);                    \
    BANK[3] = *(const bf16x8*)(Vp3 + (size_t)(JB) * 16384);                    \
  }

  // PV step for one 32-j slot: P A-frags from swizzled LDS, V from BANK.
#define SPV_PVS(BANK, SLOT)                                                    \
  {                                                                            \
    __builtin_amdgcn_s_setprio(1);                                             \
    _Pragma("unroll")                                                          \
    for (int mi = 0; mi < 3; ++mi) {                                           \
      bf16x8 ap = *(const bf16x8*)&Pl[(mi * 16 + lr) * 128 +                   \
                                      ((((SLOT) * 4 + lg) ^ (lr & 7)) << 3)];  \
      _Pragma("unroll")                                                        \
      for (int nj = 0; nj < 4; ++nj)                                           \
        accp[mi][nj] = __builtin_amdgcn_mfma_f32_16x16x32_bf16(                \
            ap, BANK[nj], accp[mi][nj], 0, 0, 0);                              \
    }                                                                          \
    __builtin_amdgcn_s_setprio(0);                                             \
  }

  SPV_STG(0, 0);
  SPV_STG(1, 1);
  SPV_STG(2, 2);
  int cur = 0;
  // P-store position: permuted within 64-block (matches vbuf j-permutation):
  // true col j = 16w+lr -> p = (w>>2)*64 + lr*4 + (w&3)
  const int cpos = ((w >> 2) << 6) | (lr << 2) | (w & 3);

  for (int jt = 0; jt < 18; ++jt) {
    f32x4 accs[3];
#pragma unroll
    for (int i = 0; i < 3; ++i) accs[i] = zero;
    for (int ks = 0; ks < 16; ++ks) {
      const int gs = jt * 16 + ks;
      if (gs < 286)       { if (w < 3) WAITVM(4); else WAITVM(2); }
      else if (gs == 286) { if (w < 3) WAITVM(2); else WAITVM(1); }
      else                WAITVM(0);
      __builtin_amdgcn_sched_barrier(0);
      __builtin_amdgcn_s_barrier();
      bf16x8 af[3], bfr;
#pragma unroll
      for (int mi = 0; mi < 3; ++mi)
        af[mi] = *(const bf16x8*)&Zs[cur][(mi * 16 + lr) * 32 + sw];
      bfr = *(const bf16x8*)&Ys[cur][(w * 16 + lr) * 32 + sw];
      __builtin_amdgcn_s_setprio(1);
#pragma unroll
      for (int mi = 0; mi < 3; ++mi)
        accs[mi] = __builtin_amdgcn_mfma_f32_16x16x32_bf16(af[mi], bfr, accs[mi], 0, 0, 0);
      __builtin_amdgcn_s_setprio(0);
      __builtin_amdgcn_s_barrier();
      if (gs + 3 < 288) { SPV_STG(gs + 3, cur) }
      cur = (cur == 2) ? 0 : cur + 1;
    }
    // exp + P(LDS) + row-sum partials
#pragma unroll
    for (int mi = 0; mi < 3; ++mi) {
#pragma unroll
      for (int r = 0; r < 4; ++r) {
        const int row = mi * 16 + lg * 4 + r;
        float pv = __expf(accs[mi][r] - 30.f);
        float sum = pv;
#pragma unroll
        for (int d = 1; d < 16; d <<= 1) sum += __shfl_xor(sum, d);
        if (lr == 0) atomicAdd(&l_run[row], sum);
        Pl[row * 128 + (cpos ^ ((row & 7) << 3))] = f2bf(pv);
      }
    }
    asm volatile("s_waitcnt lgkmcnt(0)" ::: "memory");
    __builtin_amdgcn_sched_barrier(0);
    __builtin_amdgcn_s_barrier();        // P complete for all waves
    // PV phase (double-banked V register loads from tiled vbuf)
    {
      bf16x8 vA[4], vB[4];
      __builtin_amdgcn_sched_barrier(0);
      SPV_VL(vA, jt * 4 + 0);
      SPV_VL(vB, jt * 4 + 1);
      SPV_PVS(vA, 0);
      SPV_VL(vA, jt * 4 + 2);
      SPV_PVS(vB, 1);
      SPV_VL(vB, jt * 4 + 3);
      SPV_PVS(vA, 2);
      SPV_PVS(vB, 3);
      __builtin_amdgcn_sched_barrier(0);
    }
    // next j-tile's S overwrites Pl only after 32 barriers -> safe
  }
#undef SPV_PVS
#undef SPV_VL
#undef SPV_STG

  // epilogue: normalize by running softmax denom, store oT (tiled, permuted)
  short* Db = Dp + (size_t)b * 2304 * 512;
  const int col = w * 64 + lr * 4;
  const int coff = (col >> 5) * 4096 + (col & 31);
#pragma unroll
  for (int mi = 0; mi < 3; ++mi) {
#pragma unroll
    for (int r = 0; r < 4; ++r) {
      const int row = mi * 16 + lg * 4 + r;
      const float s = 1.f / l_run[row];
      const int R = row0 + row;
      s16x4 o = { f2bf(accp[mi][0][r] * s), f2bf(accp[mi][1][r] * s),
                  f2bf(accp[mi][2][r] * s), f2bf(accp[mi][3][r] * s) };
      *(s16x4*)(Db + (R >> 7) * 65536 + coff + (R & 127) * 32) = o;
    }
  }
}

// ---------------- launcher ---------------------------------------------------
extern "C" void kernel_launch(void* const* d_in, const int* in_sizes, int n_in,
                              void* d_out, int out_size, void* d_ws, size_t ws_size,
                              hipStream_t stream) {
  const float* x     = (const float*)d_in[0];
  const float* gamma = (const float*)d_in[1];
  const float* beta  = (const float*)d_in[2];
  const float* wq    = (const float*)d_in[3];
  const float* bq    = (const float*)d_in[4];
  const float* wk    = (const float*)d_in[5];
  // d_in[6] = bk: unused (per-row constant, cancels in softmax)
  const float* wv    = (const float*)d_in[7];
  const float* bv    = (const float*)d_in[8];
  const float* wo    = (const float*)d_in[9];
  const float* bo    = (const float*)d_in[10];

  char* ws = (char*)d_ws;
  float2* stats = (float2*)(ws + 0);
  short*  Wv    = (short*)(ws + 8192);
  short*  Wo    = (short*)(ws + 532480);
  short*  WkT   = (short*)(ws + 1056768);
  short*  WqT   = (short*)(ws + 1581056);
  short*  G     = (short*)(ws + 2105344);
  float*  g0    = (float*)(ws + 2629632);
  short*  yT    = (short*)(ws + 2631680);     //  36 MB  [B] K-chunk-tiled
  short*  zoT   = (short*)(ws + 40380416);    //  36 MB  z -> oT in place, tiled
  short*  vbuf  = (short*)(ws + 78129152);    //  36 MB  [B][72][32][16][32] tiled
  float*  out   = (float*)d_out;

  const size_t sBN = (size_t)2304 * 512;

  prep_k<<<1024, 256, 0, stream>>>(wq, wk, wv, wo, Wv, Wo, WkT, WqT);
  g0_k<<<2, 256, 0, stream>>>(wk, bq, g0);
  gn_stats<<<512, 256, 0, stream>>>(x, stats);
  gn_norm_t<<<dim3(36, 8, 16), 256, 0, stream>>>(x, stats, gamma, beta, yT);
  // G[c'][c] = sum_o WkT[c'][o] * WqT[c][o]   (G stored tiled)
  gemm_k<2, false, false, false, true, 512, 512, 16><<<dim3(16, 1), 256, 0, stream>>>(
      WkT, 0, WqT, 0, G, 0, nullptr, nullptr, 512, 4, 0);
  // v[b][o][n] = sum_c Wv[o][c] * yT[b][n][c] + bv[o]  (vbuf-tiled store)
  gemm_k<3, true, true, true, false, 512, 512, 16><<<dim3(72, 16), 256, 0, stream>>>(
      Wv, 0, yT, sBN, vbuf, sBN, bv, nullptr, 2304, 4, 0);
  // z[b][i][c'] = sum_c yT[b][i][c] * G[c'][c] + g0[c']  (z stored tiled)
  gemm_k<0, false, true, true, true, 512, 512, 16><<<dim3(72, 16), 256, 0, stream>>>(
      yT, sBN, G, 0, zoT, sBN, g0, nullptr, 512, 18, 0);

  // Fused attention: S = z.yT^T, P = exp(S-30), oT = (P @ V) / rowsum(P)
  gemm_spv<<<dim3(48, 16), 512, 0, stream>>>(zoT, yT, vbuf, zoT);

  // out[b][o][n] = sum_c Wo[o][c] * oT[b][n][c] + bo[o] + x[b][o][n]
  gemm_k<1, true, true, true, false, 512, 512, 16><<<dim3(72, 16), 256, 0, stream>>>(
      Wo, 0, zoT, sBN, out, (size_t)512 * 2304, bo, x, 2304, 4, 0);
}

// Round 11
// 455.131 us; speedup vs baseline: 1.3643x; 1.3643x over previous
//
#include <hip/hip_runtime.h>

#define DI __device__ __forceinline__

typedef __attribute__((ext_vector_type(8))) short bf16x8;
typedef __attribute__((ext_vector_type(4))) short s16x4;
typedef __attribute__((ext_vector_type(4))) float f32x4;

DI short f2bf(float f) {
  unsigned u = __builtin_bit_cast(unsigned, f);
  u += 0x7FFFu + ((u >> 16) & 1u);
  return (short)(u >> 16);
}

#define WAITVM(N) asm volatile("s_waitcnt vmcnt(" #N ")" ::: "memory")
#define AS1 __attribute__((address_space(1)))
#define AS3 __attribute__((address_space(3)))

// Within-64 column permutation used for packed epilogues:
//   position p holds true column c:  p = (c&~63) + (c&15)*4 + ((c>>4)&3)
// Applied consistently to {P cols, vbuf j} (PV contraction) and
// {Wo cols, oT cols} (output-GEMM contraction) -> cancels algebraically.
//
// R8: vbuf tiled [jb=72][cb=32][16][32] (1KB-contiguous loads).
// R9: all bf16 [n][512] intermediates K-chunk-tiled:
//   off(n,k) = (n>>7)*65536 + (k>>5)*4096 + (n&127)*32 + (k&31)
// R11: depth-4 ring, 2 K-steps per barrier-pair in gemm_s/gemm_k (halves the
// ~1-2k-cycle-per-pair sync cost measured across R5/R7/R10). R10 fusion
// reverted (612 tiny pairs/block = pure sync wall).

// ---------------- prep: weights -> bf16 (+ transposed Wk/Wq for G) ----------
__global__ __launch_bounds__(256) void prep_k(
    const float* __restrict__ wq, const float* __restrict__ wk,
    const float* __restrict__ wv, const float* __restrict__ wo,
    short* __restrict__ Wv, short* __restrict__ Wo,
    short* __restrict__ WkT, short* __restrict__ WqT) {
  const int i = blockIdx.x * 256 + threadIdx.x;  // 0..262143
  const float sc = 0.04419417382415922f;         // 1/sqrt(512)
  const int o = i >> 9, c = i & 511;
  Wv[(o >> 7) * 65536 + (c >> 5) * 4096 + (o & 127) * 32 + (c & 31)] = f2bf(wv[i]);
  const int cp = (c & ~63) | ((c & 15) << 2) | ((c >> 4) & 3);
  Wo[(o >> 7) * 65536 + (cp >> 5) * 4096 + (o & 127) * 32 + (cp & 31)] = f2bf(wo[i]);
  const int tr = c * 512 + o;
  WkT[tr] = f2bf(wk[i] * sc);   // scale folded into Wk side
  WqT[tr] = f2bf(wq[i]);
}

// ---------------- g0[c'] = s * sum_o wk[o][c'] * bq[o] ----------------------
__global__ __launch_bounds__(256) void g0_k(const float* __restrict__ wk,
                                            const float* __restrict__ bq,
                                            float* __restrict__ g0) {
  const int c = blockIdx.x * 256 + threadIdx.x;  // 0..511
  float acc = 0.f;
#pragma unroll 8
  for (int o = 0; o < 512; ++o) acc += wk[o * 512 + c] * bq[o];
  g0[c] = acc * 0.04419417382415922f;
}

// ---------------- GroupNorm pass 1: per (b,g) mean/rstd ---------------------
__global__ __launch_bounds__(256) void gn_stats(const float* __restrict__ x,
                                                float2* __restrict__ stats) {
  const int bg = blockIdx.x;
  const float4* xg = (const float4*)(x + (size_t)bg * 36864);
  float s = 0.f, q = 0.f;
  for (int i = threadIdx.x; i < 9216; i += 256) {
    float4 v = xg[i];
    s += v.x + v.y + v.z + v.w;
    q += v.x * v.x + v.y * v.y + v.z * v.z + v.w * v.w;
  }
#pragma unroll
  for (int d = 1; d < 64; d <<= 1) { s += __shfl_xor(s, d); q += __shfl_xor(q, d); }
  __shared__ float rs[4], rq[4];
  const int w = threadIdx.x >> 6;
  if ((threadIdx.x & 63) == 0) { rs[w] = s; rq[w] = q; }
  __syncthreads();
  if (threadIdx.x == 0) {
    float S = rs[0] + rs[1] + rs[2] + rs[3];
    float Q = rq[0] + rq[1] + rq[2] + rq[3];
    float mean = S * (1.f / 36864.f);
    float var  = Q * (1.f / 36864.f) - mean * mean;
    float2 o; o.x = mean; o.y = rsqrtf(var + 1e-5f);
    stats[bg] = o;
  }
}

// ---------------- GroupNorm pass 2: normalize + transpose -> yT bf16 --------
__global__ __launch_bounds__(256) void gn_norm_t(
    const float* __restrict__ x, const float2* __restrict__ stats,
    const float* __restrict__ gamma, const float* __restrict__ beta,
    short* __restrict__ yT) {
  __shared__ float ts[64][68];
  const int n0 = blockIdx.x * 64, c0 = blockIdx.y * 64, b = blockIdx.z;
  const int t = threadIdx.x;
  {
    const int cw = t >> 4;
    const int n4 = (t & 15) * 4;
    const float* xb = x + ((size_t)b * 512 + c0) * 2304 + n0;
#pragma unroll
    for (int r4 = 0; r4 < 4; ++r4) {
      const int c = cw + r4 * 16;
      float4 v = *(const float4*)(xb + (size_t)c * 2304 + n4);
      *(float4*)&ts[c][n4] = v;
    }
  }
  __syncthreads();
  {
    const int c4 = t & 15;
    const int nw = t >> 4;
    const int cg = c0 + c4 * 4;
    const float2 ms = stats[b * 32 + (cg >> 4)];
    const float4 gm = *(const float4*)(gamma + cg);
    const float4 bt = *(const float4*)(beta + cg);
    const float a0 = ms.y * gm.x, a1 = ms.y * gm.y, a2 = ms.y * gm.z, a3 = ms.y * gm.w;
    const float d0 = bt.x - ms.x * a0, d1 = bt.y - ms.x * a1,
                d2 = bt.z - ms.x * a2, d3 = bt.w - ms.x * a3;
#pragma unroll
    for (int it = 0; it < 4; ++it) {
      const int no = nw + it * 16;
      const int n = n0 + no;
      const float v0 = ts[c4 * 4 + 0][no], v1 = ts[c4 * 4 + 1][no];
      const float v2 = ts[c4 * 4 + 2][no], v3 = ts[c4 * 4 + 3][no];
      s16x4 o = { f2bf(v0 * a0 + d0), f2bf(v1 * a1 + d1),
                  f2bf(v2 * a2 + d2), f2bf(v3 * a3 + d3) };
      *(s16x4*)(yT + (size_t)b * 2304 * 512 + (n >> 7) * 65536 +
                (cg >> 5) * 4096 + (n & 127) * 32 + (cg & 31)) = o;
    }
  }
}

// ---------------- Generic bf16 MFMA GEMM ------------------------------------
// D[M][N] = A[M][K] * Bt[N][K]^T, 128x128 tile, BK=32.
// R11: depth-4 LDS ring, TWO K-steps per barrier pair (32 MFMA/wave/pair).
// vmcnt(8) retires the 2 oldest stages (4 loads/wave each); fragment regs
// reused across the two halves (acc stays 4x4 -> no spill; R6 lesson).
template <int EPI, bool BIASROW, bool AT, bool BT, bool DT, int LDA, int LDB,
          int KSTEPS>
__global__ __launch_bounds__(256) void gemm_k(
    const short* __restrict__ A, size_t sA,
    const short* __restrict__ Bt, size_t sB,
    void* __restrict__ Dp, size_t sD,
    const float* __restrict__ bias, const float* __restrict__ resid,
    int N, int tilesM, int boff) {
  __shared__ short As[4][128 * 32];
  __shared__ short Bs[4][128 * 32];
  const int ba = blockIdx.y, bb = blockIdx.y + boff;
  int bx = blockIdx.x;
  bx = (bx & 7) * (int)(gridDim.x >> 3) + (bx >> 3);
  const int tm = bx % tilesM, tn = bx / tilesM;
  const int row0 = tm * 128, col0 = tn * 128;
  const int tid = threadIdx.x, lane = tid & 63, w = tid >> 6;
  const int lr = lane & 15, lg = lane >> 4;
  const short* Ab = A + (size_t)ba * sA;
  const short* Bb = Bt + (size_t)bb * sB;
  f32x4 acc[4][4];
  const f32x4 zero = {0.f, 0.f, 0.f, 0.f};
#pragma unroll
  for (int i = 0; i < 4; ++i)
#pragma unroll
    for (int j = 0; j < 4; ++j) acc[i][j] = zero;
  const int wrow = (w & 1) * 64, wcol = (w >> 1) * 64;
  const int sw = (lg ^ ((lr >> 1) & 3)) * 8;

#define GK_STAGE(KS, BUF)                                                      \
  {                                                                            \
    _Pragma("unroll")                                                          \
    for (int j = 0; j < 2; ++j) {                                              \
      const int g = (w * 2 + j) * 64 + lane;                                   \
      const int sub8 = ((g & 3) ^ ((g >> 3) & 3)) * 8;                         \
      const short* ga = AT ? (Ab + (size_t)row0 * 512 + (KS) * 4096 +          \
                              (g >> 2) * 32 + sub8)                            \
                           : (Ab + (size_t)(row0 + (g >> 2)) * LDA +           \
                              (KS) * 32 + sub8);                               \
      const short* gb = BT ? (Bb + (size_t)col0 * 512 + (KS) * 4096 +          \
                              (g >> 2) * 32 + sub8)                            \
                           : (Bb + (size_t)(col0 + (g >> 2)) * LDB +           \
                              (KS) * 32 + sub8);                               \
      __builtin_amdgcn_global_load_lds(                                        \
          (AS1 void*)ga, (AS3 void*)&As[BUF][(w * 2 + j) * 512], 16, 0, 0);    \
      __builtin_amdgcn_global_load_lds(                                        \
          (AS1 void*)gb, (AS3 void*)&Bs[BUF][(w * 2 + j) * 512], 16, 0, 0);    \
    }                                                                          \
  }

#define GK_HALF(BUF)                                                           \
  {                                                                            \
    bf16x8 af[4], bfr[4];                                                      \
    _Pragma("unroll")                                                          \
    for (int mi = 0; mi < 4; ++mi)                                             \
      af[mi] = *(const bf16x8*)&As[BUF][(wrow + mi * 16 + lr) * 32 + sw];      \
    _Pragma("unroll")                                                          \
    for (int nj = 0; nj < 4; ++nj)                                             \
      bfr[nj] = *(const bf16x8*)&Bs[BUF][(wcol + nj * 16 + lr) * 32 + sw];     \
    __builtin_amdgcn_s_setprio(1);                                             \
    _Pragma("unroll")                                                          \
    for (int mi = 0; mi < 4; ++mi)                                             \
      _Pragma("unroll")                                                        \
      for (int nj = 0; nj < 4; ++nj)                                           \
        acc[mi][nj] = __builtin_amdgcn_mfma_f32_16x16x32_bf16(                 \
            af[mi], bfr[nj], acc[mi][nj], 0, 0, 0);                            \
    __builtin_amdgcn_s_setprio(0);                                             \
  }

  GK_STAGE(0, 0);
  GK_STAGE(1, 1);
  GK_STAGE(2, 2);
  GK_STAGE(3, 3);
  for (int it = 0; it < KSTEPS / 2; ++it) {
    if (it + 1 < KSTEPS / 2) WAITVM(8);   // retires the 2 oldest stages
    else                     WAITVM(0);
    __builtin_amdgcn_sched_barrier(0);
    __builtin_amdgcn_s_barrier();          // both buffers of this pair ready
    const int b0 = (it * 2) & 3, b1 = b0 + 1;
    GK_HALF(b0);
    GK_HALF(b1);
    __builtin_amdgcn_s_barrier();          // all reads of pair done
    if (it * 2 + 4 < KSTEPS) {
      GK_STAGE(it * 2 + 4, b0);
      GK_STAGE(it * 2 + 5, b1);
    }
  }
#undef GK_HALF
#undef GK_STAGE

  const size_t bD = (size_t)bb * sD;
  if (EPI == 3) {
    const int colpos = col0 + wcol + lr * 4;
    const int jb = colpos >> 5, j5 = colpos & 31;
#pragma unroll
    for (int mi = 0; mi < 4; ++mi) {
#pragma unroll
      for (int r = 0; r < 4; ++r) {
        const int row = row0 + wrow + mi * 16 + lg * 4 + r;
        const float bv = bias[row];
        const int off = (jb * 32 + (row >> 4)) * 512 + ((row & 15) << 5) + j5;
        s16x4 o = { f2bf(acc[mi][0][r] + bv), f2bf(acc[mi][1][r] + bv),
                    f2bf(acc[mi][2][r] + bv), f2bf(acc[mi][3][r] + bv) };
        *(s16x4*)&((short*)Dp)[bD + off] = o;
      }
    }
  } else {
#pragma unroll
    for (int mi = 0; mi < 4; ++mi) {
#pragma unroll
      for (int nj = 0; nj < 4; ++nj) {
        const int col = col0 + wcol + nj * 16 + lr;
#pragma unroll
        for (int r = 0; r < 4; ++r) {
          const int row = row0 + wrow + mi * 16 + lg * 4 + r;
          float v = acc[mi][nj][r];
          if (EPI != 2) v += (BIASROW ? bias[row] : bias[col]);
          if (EPI == 1) {
            const size_t idx = bD + (size_t)row * N + col;
            ((float*)Dp)[idx] = v + resid[idx];
          } else {
            const size_t idx = bD + (DT
                ? (size_t)((row >> 7) * 65536 + (col >> 5) * 4096 +
                           (row & 127) * 32 + (col & 31))
                : (size_t)row * N + col);
            ((short*)Dp)[idx] = f2bf(v);
          }
        }
      }
    }
  }
}

// ---------------- S-GEMM, fixed-offset softmax epilogue ---------------------
// S[i][j] = z_i . y_j ; P = exp(S - 30) stored bf16, column-PERMUTED within
// 64-blocks (matches vbuf's j-permutation), packed 8B stores.
// R11: depth-4 ring, 2 K-steps per barrier pair (32 MFMA/wave/pair).
__global__ __launch_bounds__(256) void gemm_s(
    const short* __restrict__ z, const short* __restrict__ yT,
    short* __restrict__ Praw, float* __restrict__ Tsum, int b0) {
  __shared__ short As[4][128 * 32];
  __shared__ short Bs[4][128 * 32];
  const int cb = blockIdx.y;
  const int b = b0 + cb;
  int bx = blockIdx.x;                    // 324 tiles: bijective 8-way split (41/40)
  { const int xcd = bx & 7, id8 = bx >> 3;
    bx = (xcd < 4 ? xcd * 41 : 164 + (xcd - 4) * 40) + id8; }
  const int tm = bx % 18, tn = bx / 18;
  const int row0 = tm * 128, col0 = tn * 128;
  const int tid = threadIdx.x, lane = tid & 63, w = tid >> 6;
  const int lr = lane & 15, lg = lane >> 4;
  const short* Ab = z + (size_t)b * 2304 * 512;
  const short* Bb = yT + (size_t)b * 2304 * 512;
  f32x4 acc[4][4];
  const f32x4 zero = {0.f, 0.f, 0.f, 0.f};
#pragma unroll
  for (int i = 0; i < 4; ++i)
#pragma unroll
    for (int j = 0; j < 4; ++j) acc[i][j] = zero;
  const int wrow = (w & 1) * 64, wcol = (w >> 1) * 64;
  const int chalf = w >> 1;
  const int sw = (lg ^ ((lr >> 1) & 3)) * 8;

#define GS_STAGE(KS, BUF)                                                      \
  {                                                                            \
    _Pragma("unroll")                                                          \
    for (int j = 0; j < 2; ++j) {                                              \
      const int g = (w * 2 + j) * 64 + lane;                                   \
      const int sub8 = ((g & 3) ^ ((g >> 3) & 3)) * 8;                         \
      const short* ga = Ab + (size_t)row0 * 512 + (KS) * 4096 +                \
                        (g >> 2) * 32 + sub8;                                  \
      const short* gb = Bb + (size_t)col0 * 512 + (KS) * 4096 +                \
                        (g >> 2) * 32 + sub8;                                  \
      __builtin_amdgcn_global_load_lds(                                        \
          (AS1 void*)ga, (AS3 void*)&As[BUF][(w * 2 + j) * 512], 16, 0, 0);    \
      __builtin_amdgcn_global_load_lds(                                        \
          (AS1 void*)gb, (AS3 void*)&Bs[BUF][(w * 2 + j) * 512], 16, 0, 0);    \
    }                                                                          \
  }

#define GS_HALF(BUF)                                                           \
  {                                                                            \
    bf16x8 af[4], bfr[4];                                                      \
    _Pragma("unroll")                                                          \
    for (int mi = 0; mi < 4; ++mi)                                             \
      af[mi] = *(const bf16x8*)&As[BUF][(wrow + mi * 16 + lr) * 32 + sw];      \
    _Pragma("unroll")                                                          \
    for (int nj = 0; nj < 4; ++nj)                                             \
      bfr[nj] = *(const bf16x8*)&Bs[BUF][(wcol + nj * 16 + lr) * 32 + sw];     \
    __builtin_amdgcn_s_setprio(1);                                             \
    _Pragma("unroll")                                                          \
    for (int mi = 0; mi < 4; ++mi)                                             \
      _Pragma("unroll")                                                        \
      for (int nj = 0; nj < 4; ++nj)                                           \
        acc[mi][nj] = __builtin_amdgcn_mfma_f32_16x16x32_bf16(                 \
            af[mi], bfr[nj], acc[mi][nj], 0, 0, 0);                            \
    __builtin_amdgcn_s_setprio(0);                                             \
  }

  GS_STAGE(0, 0);
  GS_STAGE(1, 1);
  GS_STAGE(2, 2);
  GS_STAGE(3, 3);
  for (int it = 0; it < 8; ++it) {
    if (it < 7) WAITVM(8);
    else        WAITVM(0);
    __builtin_amdgcn_sched_barrier(0);
    __builtin_amdgcn_s_barrier();
    const int bf0 = (it * 2) & 3, bf1 = bf0 + 1;
    GS_HALF(bf0);
    GS_HALF(bf1);
    __builtin_amdgcn_s_barrier();
    if (it * 2 + 4 < 16) {
      GS_STAGE(it * 2 + 4, bf0);
      GS_STAGE(it * 2 + 5, bf1);
    }
  }
#undef GS_HALF
#undef GS_STAGE
  // epilogue: exp(acc-30), per-row partial sums, packed bf16 P store
  short* Pp = Praw + ((size_t)(cb * 18 + tn) * 2304 + row0) * 128;
  float* Ts = Tsum + (size_t)(cb * 2304 + row0) * 36 + tn * 2 + chalf;
#pragma unroll
  for (int mi = 0; mi < 4; ++mi) {
#pragma unroll
    for (int r = 0; r < 4; ++r) {
      const int row = wrow + mi * 16 + lg * 4 + r;
      float pv0 = __expf(acc[mi][0][r] - 30.f);
      float pv1 = __expf(acc[mi][1][r] - 30.f);
      float pv2 = __expf(acc[mi][2][r] - 30.f);
      float pv3 = __expf(acc[mi][3][r] - 30.f);
      float sum = pv0 + pv1 + pv2 + pv3;
#pragma unroll
      for (int d = 1; d < 16; d <<= 1) sum += __shfl_xor(sum, d);
      if (lr == 0) Ts[(size_t)row * 36] = sum;
      s16x4 o = { f2bf(pv0), f2bf(pv1), f2bf(pv2), f2bf(pv3) };
      *(s16x4*)(Pp + (size_t)row * 128 + wcol + lr * 4) = o;
    }
  }
}

// ---------------- linv[row] = 1 / sum_t Tsum[row][t] ------------------------
__global__ __launch_bounds__(256) void sum_k(
    const float* __restrict__ Tsum, float* __restrict__ linv, int nrows) {
  const int r = blockIdx.x * 256 + threadIdx.x;
  if (r >= nrows) return;
  const float* ts = Tsum + (size_t)r * 36;
  float l = 0.f;
#pragma unroll
  for (int t = 0; t < 36; ++t) l += ts[t];
  linv[r] = 1.f / l;
}

// ---------------- PV GEMM (R9 form: R5 structure + tiled-V loads) -----------
// oT[i][c] = linv[i] * sum_j Praw[i][j] * v[c][j]  (j,c in permuted space)
// 16 tm-tiles x 16 batches = 256 blocks = exactly 1 block/CU. 8 waves; wave w
// owns c-slice [64w,64w+64). A (P) staged in LDS depth-3 ring; V loads from
// tiled vbuf (1KB contiguous). oT stored K-chunk-tiled for the out-GEMM.
__global__ __launch_bounds__(512) void gemm_pv(
    const short* __restrict__ Praw, const float* __restrict__ linv,
    const short* __restrict__ vsrc, short* __restrict__ Dp, int b0) {
  __shared__ short As[3][144 * 32];   // 3 x 9 KB
  int tm, cb;
  if (gridDim.y == 16) {
    const int id = blockIdx.y * 16 + blockIdx.x;   // 256 blocks
    const int xcd = id & 7, r = id >> 3;           // r in [0,32)
    cb = xcd * 2 + (r >= 16 ? 1 : 0);
    tm = r & 15;
  } else {
    cb = blockIdx.y; tm = blockIdx.x;
  }
  const int bb = b0 + cb;
  const int row0 = tm * 144;
  const int tid = threadIdx.x, lane = tid & 63, w = tid >> 6;  // 8 waves
  const int lr = lane & 15, lg = lane >> 4;
  const short* Ab = Praw + (size_t)cb * 18 * 2304 * 128;
  const short* Bb = vsrc + (size_t)bb * 512 * 2304;
  const short* Bp0 = Bb + (w * 4 + 0) * 512 + lr * 32 + lg * 8;
  const short* Bp1 = Bb + (w * 4 + 1) * 512 + lr * 32 + lg * 8;
  const short* Bp2 = Bb + (w * 4 + 2) * 512 + lr * 32 + lg * 8;
  const short* Bp3 = Bb + (w * 4 + 3) * 512 + lr * 32 + lg * 8;
  f32x4 acc[9][4];
  const f32x4 zero = {0.f, 0.f, 0.f, 0.f};
#pragma unroll
  for (int i = 0; i < 9; ++i)
#pragma unroll
    for (int j = 0; j < 4; ++j) acc[i][j] = zero;
  const int sw = (lg ^ ((lr >> 1) & 3)) * 8;

#define PVA_STAGE(KS, BUF)                                                     \
  {                                                                            \
    const int kt = (KS) >> 2, k32 = ((KS) & 3) * 32;                           \
    {                                                                          \
      const int g = tid;                                                       \
      const short* ga = Ab + ((size_t)kt * 2304 + row0 + (g >> 2)) * 128 +     \
                        k32 + (((g & 3) ^ ((g >> 3) & 3)) * 8);                \
      __builtin_amdgcn_global_load_lds(                                        \
          (AS1 void*)ga, (AS3 void*)&As[BUF][w * 512], 16, 0, 0);              \
    }                                                                          \
    if (w == 0) {                                                              \
      const int g = 512 + tid;                                                 \
      const short* ga = Ab + ((size_t)kt * 2304 + row0 + (g >> 2)) * 128 +     \
                        k32 + (((g & 3) ^ ((g >> 3) & 3)) * 8);                \
      __builtin_amdgcn_global_load_lds(                                        \
          (AS1 void*)ga, (AS3 void*)&As[BUF][4096], 16, 0, 0);                 \
    }                                                                          \
  }

#define PV_BLOAD(KS, BR)                                                       \
  {                                                                            \
    BR[0] = *(const bf16x8*)(Bp0 + (KS) * 16384);                              \
    BR[1] = *(const bf16x8*)(Bp1 + (KS) * 16384);                              \
    BR[2] = *(const bf16x8*)(Bp2 + (KS) * 16384);                              \
    BR[3] = *(const bf16x8*)(Bp3 + (KS) * 16384);                              \
  }

#define PV_ITER(KS, BUSE, BFILL)                                               \
  {                                                                            \
    if ((KS) < 70)       { if (w == 0) WAITVM(12); else WAITVM(10); }          \
    else if ((KS) == 70) { if (w == 0) WAITVM(10); else WAITVM(8); }           \
    else                 WAITVM(4);                                            \
    __builtin_amdgcn_sched_barrier(0);                                         \
    __builtin_amdgcn_s_barrier();                                              \
    bf16x8 af[9];                                                              \
    _Pragma("unroll")                                                          \
    for (int mi = 0; mi < 9; ++mi)                                             \
      af[mi] = *(const bf16x8*)&As[cur][(mi * 16 + lr) * 32 + sw];             \
    __builtin_amdgcn_s_setprio(1);                                             \
    _Pragma("unroll")                                                          \
    for (int mi = 0; mi < 9; ++mi)                                             \
      _Pragma("unroll")                                                        \
      for (int nj = 0; nj < 4; ++nj)                                           \
        acc[mi][nj] = __builtin_amdgcn_mfma_f32_16x16x32_bf16(                 \
            af[mi], BUSE[nj], acc[mi][nj], 0, 0, 0);                           \
    __builtin_amdgcn_s_setprio(0);                                             \
    __builtin_amdgcn_s_barrier();                                              \
    if ((KS) + 2 < 72) PV_BLOAD((KS) + 2, BFILL);                              \
    if ((KS) + 3 < 72) PVA_STAGE((KS) + 3, cur);                               \
    cur = (cur == 2) ? 0 : cur + 1;                                            \
  }

  bf16x8 bA[4], bB[4];
  PVA_STAGE(0, 0);
  PVA_STAGE(1, 1);
  PVA_STAGE(2, 2);
  PV_BLOAD(0, bA);
  PV_BLOAD(1, bB);
  int cur = 0;
  for (int ks = 0; ks < 72; ks += 2) {
    PV_ITER(ks, bA, bA);
    PV_ITER(ks + 1, bB, bB);
  }
#undef PV_ITER
#undef PV_BLOAD
#undef PVA_STAGE

  const float* lv = linv + (size_t)cb * 2304 + row0;
  short* Db = Dp + (size_t)bb * 2304 * 512;
  const int col = w * 64 + lr * 4;                 // permuted position
  const int coff = (col >> 5) * 4096 + (col & 31); // tiled col part
#pragma unroll
  for (int mi = 0; mi < 9; ++mi) {
#pragma unroll
    for (int r = 0; r < 4; ++r) {
      const int row = mi * 16 + lg * 4 + r;
      const float s = lv[row];
      const int R = row0 + row;
      s16x4 o = { f2bf(acc[mi][0][r] * s), f2bf(acc[mi][1][r] * s),
                  f2bf(acc[mi][2][r] * s), f2bf(acc[mi][3][r] * s) };
      *(s16x4*)(Db + (R >> 7) * 65536 + coff + (R & 127) * 32) = o;
    }
  }
}

// ---------------- launcher ---------------------------------------------------
extern "C" void kernel_launch(void* const* d_in, const int* in_sizes, int n_in,
                              void* d_out, int out_size, void* d_ws, size_t ws_size,
                              hipStream_t stream) {
  const float* x     = (const float*)d_in[0];
  const float* gamma = (const float*)d_in[1];
  const float* beta  = (const float*)d_in[2];
  const float* wq    = (const float*)d_in[3];
  const float* bq    = (const float*)d_in[4];
  const float* wk    = (const float*)d_in[5];
  // d_in[6] = bk: unused (per-row constant, cancels in softmax)
  const float* wv    = (const float*)d_in[7];
  const float* bv    = (const float*)d_in[8];
  const float* wo    = (const float*)d_in[9];
  const float* bo    = (const float*)d_in[10];

  char* ws = (char*)d_ws;
  float2* stats = (float2*)(ws + 0);
  short*  Wv    = (short*)(ws + 8192);
  short*  Wo    = (short*)(ws + 532480);
  short*  WkT   = (short*)(ws + 1056768);
  short*  WqT   = (short*)(ws + 1581056);
  short*  G     = (short*)(ws + 2105344);
  float*  g0    = (float*)(ws + 2629632);
  short*  yT    = (short*)(ws + 2631680);     //  36 MB  [B] K-chunk-tiled
  short*  zoT   = (short*)(ws + 40380416);    //  36 MB  z -> oT, tiled
  short*  vbuf  = (short*)(ws + 78129152);    //  36 MB  [B][72][32][16][32] tiled
  short*  Praw  = (short*)(ws + 115877888);   //  CH * 10,616,832 [b][18][2304][128]
  float*  out   = (float*)d_out;

  const size_t base = 115877888ull;
  const size_t per  = 10616832ull + 331776ull + 9216ull;  // Praw+Tsum+linv
  int CH = 16;
  if (ws_size < base + 16 * per) CH = (ws_size >= base + 8 * per) ? 8 : 4;
  float* Tsum = (float*)(ws + base + (size_t)CH * 10616832ull);
  float* linv = (float*)(ws + base + (size_t)CH * (10616832ull + 331776ull));

  const size_t sBN = (size_t)2304 * 512;

  prep_k<<<1024, 256, 0, stream>>>(wq, wk, wv, wo, Wv, Wo, WkT, WqT);
  g0_k<<<2, 256, 0, stream>>>(wk, bq, g0);
  gn_stats<<<512, 256, 0, stream>>>(x, stats);
  gn_norm_t<<<dim3(36, 8, 16), 256, 0, stream>>>(x, stats, gamma, beta, yT);
  // G[c'][c] = sum_o WkT[c'][o] * WqT[c][o]   (G stored tiled)
  gemm_k<2, false, false, false, true, 512, 512, 16><<<dim3(16, 1), 256, 0, stream>>>(
      WkT, 0, WqT, 0, G, 0, nullptr, nullptr, 512, 4, 0);
  // v[b][o][n] = sum_c Wv[o][c] * yT[b][n][c] + bv[o]  (vbuf-tiled store)
  gemm_k<3, true, true, true, false, 512, 512, 16><<<dim3(72, 16), 256, 0, stream>>>(
      Wv, 0, yT, sBN, vbuf, sBN, bv, nullptr, 2304, 4, 0);
  // z[b][i][c'] = sum_c yT[b][i][c] * G[c'][c] + g0[c']  (z stored tiled)
  gemm_k<0, false, true, true, true, 512, 512, 16><<<dim3(72, 16), 256, 0, stream>>>(
      yT, sBN, G, 0, zoT, sBN, g0, nullptr, 512, 18, 0);

  for (int b0 = 0; b0 < 16; b0 += CH) {
    const int n = (16 - b0 < CH) ? (16 - b0) : CH;
    gemm_s<<<dim3(324, n), 256, 0, stream>>>(zoT, yT, Praw, Tsum, b0);
    sum_k<<<(n * 2304 + 255) / 256, 256, 0, stream>>>(Tsum, linv, n * 2304);
    gemm_pv<<<dim3(16, n), 512, 0, stream>>>(Praw, linv, vbuf, zoT, b0);
  }
  // out[b][o][n] = sum_c Wo[o][c] * oT[b][n][c] + bo[o] + x[b][o][n]
  gemm_k<1, true, true, true, false, 512, 512, 16><<<dim3(72, 16), 256, 0, stream>>>(
      Wo, 0, zoT, sBN, out, (size_t)512 * 2304, bo, x, 2304, 4, 0);
}

// Round 12
// 425.942 us; speedup vs baseline: 1.4578x; 1.0685x over previous
//
#include <hip/hip_runtime.h>

#define DI __device__ __forceinline__

typedef __attribute__((ext_vector_type(8))) short bf16x8;
typedef __attribute__((ext_vector_type(4))) short s16x4;
typedef __attribute__((ext_vector_type(4))) float f32x4;

DI short f2bf(float f) {
  unsigned u = __builtin_bit_cast(unsigned, f);
  u += 0x7FFFu + ((u >> 16) & 1u);
  return (short)(u >> 16);
}

#define WAITVM(N) asm volatile("s_waitcnt vmcnt(" #N ")" ::: "memory")
#define AS1 __attribute__((address_space(1)))
#define AS3 __attribute__((address_space(3)))

// Within-64 column permutation used for packed epilogues:
//   position p holds true column c:  p = (c&~63) + (c&15)*4 + ((c>>4)&3)
// Applied consistently to {P cols, vbuf j} (PV contraction) and
// {Wo cols, oT cols} (output-GEMM contraction) -> cancels algebraically.
//
// R8: vbuf tiled [jb=72][cb=32][16][32] (1KB-contiguous loads).
// R9: all bf16 [n][512] intermediates K-chunk-tiled:
//   off(n,k) = (n>>7)*65536 + (k>>5)*4096 + (n&127)*32 + (k&31)
// R12: R11 depth-4 reverted (cost a resident block: 30.6->20.6% occ, +20us).
// NEW: dispatch-linear XCD-batch grouping in gemm_s/gemm_k — each XCD owns
// 2 batches so the ~96 resident blocks/XCD have a <4MB L2 working set
// (was ~6MB spanning 2.4 batches -> 3x refetch, FETCH 208MB vs 72 compulsory).

// ---------------- prep: weights -> bf16 (+ transposed Wk/Wq for G) ----------
__global__ __launch_bounds__(256) void prep_k(
    const float* __restrict__ wq, const float* __restrict__ wk,
    const float* __restrict__ wv, const float* __restrict__ wo,
    short* __restrict__ Wv, short* __restrict__ Wo,
    short* __restrict__ WkT, short* __restrict__ WqT) {
  const int i = blockIdx.x * 256 + threadIdx.x;  // 0..262143
  const float sc = 0.04419417382415922f;         // 1/sqrt(512)
  const int o = i >> 9, c = i & 511;
  Wv[(o >> 7) * 65536 + (c >> 5) * 4096 + (o & 127) * 32 + (c & 31)] = f2bf(wv[i]);
  const int cp = (c & ~63) | ((c & 15) << 2) | ((c >> 4) & 3);
  Wo[(o >> 7) * 65536 + (cp >> 5) * 4096 + (o & 127) * 32 + (cp & 31)] = f2bf(wo[i]);
  const int tr = c * 512 + o;
  WkT[tr] = f2bf(wk[i] * sc);   // scale folded into Wk side
  WqT[tr] = f2bf(wq[i]);
}

// ---------------- g0[c'] = s * sum_o wk[o][c'] * bq[o] ----------------------
__global__ __launch_bounds__(256) void g0_k(const float* __restrict__ wk,
                                            const float* __restrict__ bq,
                                            float* __restrict__ g0) {
  const int c = blockIdx.x * 256 + threadIdx.x;  // 0..511
  float acc = 0.f;
#pragma unroll 8
  for (int o = 0; o < 512; ++o) acc += wk[o * 512 + c] * bq[o];
  g0[c] = acc * 0.04419417382415922f;
}

// ---------------- GroupNorm pass 1: per (b,g) mean/rstd ---------------------
__global__ __launch_bounds__(256) void gn_stats(const float* __restrict__ x,
                                                float2* __restrict__ stats) {
  const int bg = blockIdx.x;
  const float4* xg = (const float4*)(x + (size_t)bg * 36864);
  float s = 0.f, q = 0.f;
  for (int i = threadIdx.x; i < 9216; i += 256) {
    float4 v = xg[i];
    s += v.x + v.y + v.z + v.w;
    q += v.x * v.x + v.y * v.y + v.z * v.z + v.w * v.w;
  }
#pragma unroll
  for (int d = 1; d < 64; d <<= 1) { s += __shfl_xor(s, d); q += __shfl_xor(q, d); }
  __shared__ float rs[4], rq[4];
  const int w = threadIdx.x >> 6;
  if ((threadIdx.x & 63) == 0) { rs[w] = s; rq[w] = q; }
  __syncthreads();
  if (threadIdx.x == 0) {
    float S = rs[0] + rs[1] + rs[2] + rs[3];
    float Q = rq[0] + rq[1] + rq[2] + rq[3];
    float mean = S * (1.f / 36864.f);
    float var  = Q * (1.f / 36864.f) - mean * mean;
    float2 o; o.x = mean; o.y = rsqrtf(var + 1e-5f);
    stats[bg] = o;
  }
}

// ---------------- GroupNorm pass 2: normalize + transpose -> yT bf16 --------
__global__ __launch_bounds__(256) void gn_norm_t(
    const float* __restrict__ x, const float2* __restrict__ stats,
    const float* __restrict__ gamma, const float* __restrict__ beta,
    short* __restrict__ yT) {
  __shared__ float ts[64][68];
  const int n0 = blockIdx.x * 64, c0 = blockIdx.y * 64, b = blockIdx.z;
  const int t = threadIdx.x;
  {
    const int cw = t >> 4;
    const int n4 = (t & 15) * 4;
    const float* xb = x + ((size_t)b * 512 + c0) * 2304 + n0;
#pragma unroll
    for (int r4 = 0; r4 < 4; ++r4) {
      const int c = cw + r4 * 16;
      float4 v = *(const float4*)(xb + (size_t)c * 2304 + n4);
      *(float4*)&ts[c][n4] = v;
    }
  }
  __syncthreads();
  {
    const int c4 = t & 15;
    const int nw = t >> 4;
    const int cg = c0 + c4 * 4;
    const float2 ms = stats[b * 32 + (cg >> 4)];
    const float4 gm = *(const float4*)(gamma + cg);
    const float4 bt = *(const float4*)(beta + cg);
    const float a0 = ms.y * gm.x, a1 = ms.y * gm.y, a2 = ms.y * gm.z, a3 = ms.y * gm.w;
    const float d0 = bt.x - ms.x * a0, d1 = bt.y - ms.x * a1,
                d2 = bt.z - ms.x * a2, d3 = bt.w - ms.x * a3;
#pragma unroll
    for (int it = 0; it < 4; ++it) {
      const int no = nw + it * 16;
      const int n = n0 + no;
      const float v0 = ts[c4 * 4 + 0][no], v1 = ts[c4 * 4 + 1][no];
      const float v2 = ts[c4 * 4 + 2][no], v3 = ts[c4 * 4 + 3][no];
      s16x4 o = { f2bf(v0 * a0 + d0), f2bf(v1 * a1 + d1),
                  f2bf(v2 * a2 + d2), f2bf(v3 * a3 + d3) };
      *(s16x4*)(yT + (size_t)b * 2304 * 512 + (n >> 7) * 65536 +
                (cg >> 5) * 4096 + (n & 127) * 32 + (cg & 31)) = o;
    }
  }
}

// ---------------- Generic bf16 MFMA GEMM (depth-3 ring, R9 form) ------------
// D[M][N] = A[M][K] * Bt[N][K]^T, 128x128 tile, BK=32.
// R12: dispatch-linear XCD-batch grouping (2 batches/XCD) when gridDim.y==16.
template <int EPI, bool BIASROW, bool AT, bool BT, bool DT, int LDA, int LDB,
          int KSTEPS>
__global__ __launch_bounds__(256) void gemm_k(
    const short* __restrict__ A, size_t sA,
    const short* __restrict__ Bt, size_t sB,
    void* __restrict__ Dp, size_t sD,
    const float* __restrict__ bias, const float* __restrict__ resid,
    int N, int tilesM, int boff) {
  __shared__ short As[3][128 * 32];
  __shared__ short Bs[3][128 * 32];
  int bx, cb;
  if (gridDim.y == 16) {
    const int gx = gridDim.x;                       // 72
    const int id = blockIdx.y * gx + blockIdx.x;    // dispatch-linear
    const int xcd = id & 7, r = id >> 3;            // r in [0, 2*gx)
    cb = xcd * 2 + (r >= gx ? 1 : 0);               // this XCD's 2 batches
    bx = (r >= gx) ? r - gx : r;
  } else {
    bx = blockIdx.x;
    bx = (bx & 7) * (int)(gridDim.x >> 3) + (bx >> 3);
    cb = blockIdx.y;
  }
  const int ba = cb, bb = cb + boff;
  const int tm = bx % tilesM, tn = bx / tilesM;
  const int row0 = tm * 128, col0 = tn * 128;
  const int tid = threadIdx.x, lane = tid & 63, w = tid >> 6;
  const int lr = lane & 15, lg = lane >> 4;
  const short* Ab = A + (size_t)ba * sA;
  const short* Bb = Bt + (size_t)bb * sB;
  f32x4 acc[4][4];
  const f32x4 zero = {0.f, 0.f, 0.f, 0.f};
#pragma unroll
  for (int i = 0; i < 4; ++i)
#pragma unroll
    for (int j = 0; j < 4; ++j) acc[i][j] = zero;
  const int wrow = (w & 1) * 64, wcol = (w >> 1) * 64;
  const int sw = (lg ^ ((lr >> 1) & 3)) * 8;

#define GK_STAGE(KS, BUF)                                                      \
  {                                                                            \
    _Pragma("unroll")                                                          \
    for (int j = 0; j < 2; ++j) {                                              \
      const int g = (w * 2 + j) * 64 + lane;                                   \
      const int sub8 = ((g & 3) ^ ((g >> 3) & 3)) * 8;                         \
      const short* ga = AT ? (Ab + (size_t)row0 * 512 + (KS) * 4096 +          \
                              (g >> 2) * 32 + sub8)                            \
                           : (Ab + (size_t)(row0 + (g >> 2)) * LDA +           \
                              (KS) * 32 + sub8);                               \
      const short* gb = BT ? (Bb + (size_t)col0 * 512 + (KS) * 4096 +          \
                              (g >> 2) * 32 + sub8)                            \
                           : (Bb + (size_t)(col0 + (g >> 2)) * LDB +           \
                              (KS) * 32 + sub8);                               \
      __builtin_amdgcn_global_load_lds(                                        \
          (AS1 void*)ga, (AS3 void*)&As[BUF][(w * 2 + j) * 512], 16, 0, 0);    \
      __builtin_amdgcn_global_load_lds(                                        \
          (AS1 void*)gb, (AS3 void*)&Bs[BUF][(w * 2 + j) * 512], 16, 0, 0);    \
    }                                                                          \
  }

  GK_STAGE(0, 0);
  GK_STAGE(1, 1);
  GK_STAGE(2, 2);
  int cur = 0;
  for (int ks = 0; ks < KSTEPS; ++ks) {
    if (ks + 2 < KSTEPS)      WAITVM(8);
    else if (ks + 1 < KSTEPS) WAITVM(4);
    else                      WAITVM(0);
    __builtin_amdgcn_sched_barrier(0);
    __builtin_amdgcn_s_barrier();
    bf16x8 af[4], bfr[4];
#pragma unroll
    for (int mi = 0; mi < 4; ++mi)
      af[mi] = *(const bf16x8*)&As[cur][(wrow + mi * 16 + lr) * 32 + sw];
#pragma unroll
    for (int nj = 0; nj < 4; ++nj)
      bfr[nj] = *(const bf16x8*)&Bs[cur][(wcol + nj * 16 + lr) * 32 + sw];
    __builtin_amdgcn_s_setprio(1);
#pragma unroll
    for (int mi = 0; mi < 4; ++mi)
#pragma unroll
      for (int nj = 0; nj < 4; ++nj)
        acc[mi][nj] = __builtin_amdgcn_mfma_f32_16x16x32_bf16(af[mi], bfr[nj], acc[mi][nj], 0, 0, 0);
    __builtin_amdgcn_s_setprio(0);
    __builtin_amdgcn_s_barrier();
    if (ks + 3 < KSTEPS) { GK_STAGE(ks + 3, cur) }
    cur = (cur == 2) ? 0 : cur + 1;
  }
#undef GK_STAGE

  const size_t bD = (size_t)bb * sD;
  if (EPI == 3) {
    const int colpos = col0 + wcol + lr * 4;
    const int jb = colpos >> 5, j5 = colpos & 31;
#pragma unroll
    for (int mi = 0; mi < 4; ++mi) {
#pragma unroll
      for (int r = 0; r < 4; ++r) {
        const int row = row0 + wrow + mi * 16 + lg * 4 + r;
        const float bv = bias[row];
        const int off = (jb * 32 + (row >> 4)) * 512 + ((row & 15) << 5) + j5;
        s16x4 o = { f2bf(acc[mi][0][r] + bv), f2bf(acc[mi][1][r] + bv),
                    f2bf(acc[mi][2][r] + bv), f2bf(acc[mi][3][r] + bv) };
        *(s16x4*)&((short*)Dp)[bD + off] = o;
      }
    }
  } else {
#pragma unroll
    for (int mi = 0; mi < 4; ++mi) {
#pragma unroll
      for (int nj = 0; nj < 4; ++nj) {
        const int col = col0 + wcol + nj * 16 + lr;
#pragma unroll
        for (int r = 0; r < 4; ++r) {
          const int row = row0 + wrow + mi * 16 + lg * 4 + r;
          float v = acc[mi][nj][r];
          if (EPI != 2) v += (BIASROW ? bias[row] : bias[col]);
          if (EPI == 1) {
            const size_t idx = bD + (size_t)row * N + col;
            ((float*)Dp)[idx] = v + resid[idx];
          } else {
            const size_t idx = bD + (DT
                ? (size_t)((row >> 7) * 65536 + (col >> 5) * 4096 +
                           (row & 127) * 32 + (col & 31))
                : (size_t)row * N + col);
            ((short*)Dp)[idx] = f2bf(v);
          }
        }
      }
    }
  }
}

// ---------------- S-GEMM, fixed-offset softmax epilogue (R9 + grouping) -----
// S[i][j] = z_i . y_j ; P = exp(S - 30) stored bf16, column-PERMUTED within
// 64-blocks (matches vbuf's j-permutation), packed 8B stores.
// R12: XCD owns 2 batches, tm-fastest sweep -> per-XCD working set
// ~ all-z (2.25MB) + ~6 yT panels (0.8MB) < 4MB L2.
__global__ __launch_bounds__(256) void gemm_s(
    const short* __restrict__ z, const short* __restrict__ yT,
    short* __restrict__ Praw, float* __restrict__ Tsum, int b0) {
  __shared__ short As[3][128 * 32];
  __shared__ short Bs[3][128 * 32];
  int tm, tn, cb;
  if (gridDim.y == 16) {
    const int id = blockIdx.y * 324 + blockIdx.x;   // dispatch-linear
    const int xcd = id & 7, r = id >> 3;            // r in [0,648)
    cb = xcd * 2 + (r >= 324 ? 1 : 0);
    const int rr = (r >= 324) ? r - 324 : r;
    tm = rr % 18; tn = rr / 18;                     // tm fastest
  } else {
    int bx = blockIdx.x;
    const int xcd = bx & 7, id8 = bx >> 3;
    bx = (xcd < 4 ? xcd * 41 : 164 + (xcd - 4) * 40) + id8;
    tm = bx % 18; tn = bx / 18; cb = blockIdx.y;
  }
  const int b = b0 + cb;
  const int row0 = tm * 128, col0 = tn * 128;
  const int tid = threadIdx.x, lane = tid & 63, w = tid >> 6;
  const int lr = lane & 15, lg = lane >> 4;
  const short* Ab = z + (size_t)b * 2304 * 512;
  const short* Bb = yT + (size_t)b * 2304 * 512;
  f32x4 acc[4][4];
  const f32x4 zero = {0.f, 0.f, 0.f, 0.f};
#pragma unroll
  for (int i = 0; i < 4; ++i)
#pragma unroll
    for (int j = 0; j < 4; ++j) acc[i][j] = zero;
  const int wrow = (w & 1) * 64, wcol = (w >> 1) * 64;
  const int chalf = w >> 1;
  const int sw = (lg ^ ((lr >> 1) & 3)) * 8;

#define GS_STAGE(KS, BUF)                                                      \
  {                                                                            \
    _Pragma("unroll")                                                          \
    for (int j = 0; j < 2; ++j) {                                              \
      const int g = (w * 2 + j) * 64 + lane;                                   \
      const int sub8 = ((g & 3) ^ ((g >> 3) & 3)) * 8;                         \
      const short* ga = Ab + (size_t)row0 * 512 + (KS) * 4096 +                \
                        (g >> 2) * 32 + sub8;                                  \
      const short* gb = Bb + (size_t)col0 * 512 + (KS) * 4096 +                \
                        (g >> 2) * 32 + sub8;                                  \
      __builtin_amdgcn_global_load_lds(                                        \
          (AS1 void*)ga, (AS3 void*)&As[BUF][(w * 2 + j) * 512], 16, 0, 0);    \
      __builtin_amdgcn_global_load_lds(                                        \
          (AS1 void*)gb, (AS3 void*)&Bs[BUF][(w * 2 + j) * 512], 16, 0, 0);    \
    }                                                                          \
  }

  GS_STAGE(0, 0);
  GS_STAGE(1, 1);
  GS_STAGE(2, 2);
  int cur = 0;
  for (int ks = 0; ks < 16; ++ks) {
    if (ks < 14)      WAITVM(8);
    else if (ks < 15) WAITVM(4);
    else              WAITVM(0);
    __builtin_amdgcn_sched_barrier(0);
    __builtin_amdgcn_s_barrier();
    bf16x8 af[4], bfr[4];
#pragma unroll
    for (int mi = 0; mi < 4; ++mi)
      af[mi] = *(const bf16x8*)&As[cur][(wrow + mi * 16 + lr) * 32 + sw];
#pragma unroll
    for (int nj = 0; nj < 4; ++nj)
      bfr[nj] = *(const bf16x8*)&Bs[cur][(wcol + nj * 16 + lr) * 32 + sw];
    __builtin_amdgcn_s_setprio(1);
#pragma unroll
    for (int mi = 0; mi < 4; ++mi)
#pragma unroll
      for (int nj = 0; nj < 4; ++nj)
        acc[mi][nj] = __builtin_amdgcn_mfma_f32_16x16x32_bf16(af[mi], bfr[nj], acc[mi][nj], 0, 0, 0);
    __builtin_amdgcn_s_setprio(0);
    __builtin_amdgcn_s_barrier();
    if (ks + 3 < 16) { GS_STAGE(ks + 3, cur) }
    cur = (cur == 2) ? 0 : cur + 1;
  }
#undef GS_STAGE
  // epilogue: exp(acc-30), per-row partial sums, packed bf16 P store
  short* Pp = Praw + ((size_t)(cb * 18 + tn) * 2304 + row0) * 128;
  float* Ts = Tsum + (size_t)(cb * 2304 + row0) * 36 + tn * 2 + chalf;
#pragma unroll
  for (int mi = 0; mi < 4; ++mi) {
#pragma unroll
    for (int r = 0; r < 4; ++r) {
      const int row = wrow + mi * 16 + lg * 4 + r;
      float pv0 = __expf(acc[mi][0][r] - 30.f);
      float pv1 = __expf(acc[mi][1][r] - 30.f);
      float pv2 = __expf(acc[mi][2][r] - 30.f);
      float pv3 = __expf(acc[mi][3][r] - 30.f);
      float sum = pv0 + pv1 + pv2 + pv3;
#pragma unroll
      for (int d = 1; d < 16; d <<= 1) sum += __shfl_xor(sum, d);
      if (lr == 0) Ts[(size_t)row * 36] = sum;
      s16x4 o = { f2bf(pv0), f2bf(pv1), f2bf(pv2), f2bf(pv3) };
      *(s16x4*)(Pp + (size_t)row * 128 + wcol + lr * 4) = o;
    }
  }
}

// ---------------- linv[row] = 1 / sum_t Tsum[row][t] ------------------------
__global__ __launch_bounds__(256) void sum_k(
    const float* __restrict__ Tsum, float* __restrict__ linv, int nrows) {
  const int r = blockIdx.x * 256 + threadIdx.x;
  if (r >= nrows) return;
  const float* ts = Tsum + (size_t)r * 36;
  float l = 0.f;
#pragma unroll
  for (int t = 0; t < 36; ++t) l += ts[t];
  linv[r] = 1.f / l;
}

// ---------------- PV GEMM (R9 form: R5 structure + tiled-V loads) -----------
// oT[i][c] = linv[i] * sum_j Praw[i][j] * v[c][j]  (j,c in permuted space)
// 16 tm-tiles x 16 batches = 256 blocks = exactly 1 block/CU. 8 waves; wave w
// owns c-slice [64w,64w+64). A (P) staged in LDS depth-3 ring; V loads from
// tiled vbuf (1KB contiguous). oT stored K-chunk-tiled for the out-GEMM.
__global__ __launch_bounds__(512) void gemm_pv(
    const short* __restrict__ Praw, const float* __restrict__ linv,
    const short* __restrict__ vsrc, short* __restrict__ Dp, int b0) {
  __shared__ short As[3][144 * 32];   // 3 x 9 KB
  int tm, cb;
  if (gridDim.y == 16) {
    const int id = blockIdx.y * 16 + blockIdx.x;   // 256 blocks
    const int xcd = id & 7, r = id >> 3;           // r in [0,32)
    cb = xcd * 2 + (r >= 16 ? 1 : 0);
    tm = r & 15;
  } else {
    cb = blockIdx.y; tm = blockIdx.x;
  }
  const int bb = b0 + cb;
  const int row0 = tm * 144;
  const int tid = threadIdx.x, lane = tid & 63, w = tid >> 6;  // 8 waves
  const int lr = lane & 15, lg = lane >> 4;
  const short* Ab = Praw + (size_t)cb * 18 * 2304 * 128;
  const short* Bb = vsrc + (size_t)bb * 512 * 2304;
  const short* Bp0 = Bb + (w * 4 + 0) * 512 + lr * 32 + lg * 8;
  const short* Bp1 = Bb + (w * 4 + 1) * 512 + lr * 32 + lg * 8;
  const short* Bp2 = Bb + (w * 4 + 2) * 512 + lr * 32 + lg * 8;
  const short* Bp3 = Bb + (w * 4 + 3) * 512 + lr * 32 + lg * 8;
  f32x4 acc[9][4];
  const f32x4 zero = {0.f, 0.f, 0.f, 0.f};
#pragma unroll
  for (int i = 0; i < 9; ++i)
#pragma unroll
    for (int j = 0; j < 4; ++j) acc[i][j] = zero;
  const int sw = (lg ^ ((lr >> 1) & 3)) * 8;

#define PVA_STAGE(KS, BUF)                                                     \
  {                                                                            \
    const int kt = (KS) >> 2, k32 = ((KS) & 3) * 32;                           \
    {                                                                          \
      const int g = tid;                                                       \
      const short* ga = Ab + ((size_t)kt * 2304 + row0 + (g >> 2)) * 128 +     \
                        k32 + (((g & 3) ^ ((g >> 3) & 3)) * 8);                \
      __builtin_amdgcn_global_load_lds(                                        \
          (AS1 void*)ga, (AS3 void*)&As[BUF][w * 512], 16, 0, 0);              \
    }                                                                          \
    if (w == 0) {                                                              \
      const int g = 512 + tid;                                                 \
      const short* ga = Ab + ((size_t)kt * 2304 + row0 + (g >> 2)) * 128 +     \
                        k32 + (((g & 3) ^ ((g >> 3) & 3)) * 8);                \
      __builtin_amdgcn_global_load_lds(                                        \
          (AS1 void*)ga, (AS3 void*)&As[BUF][4096], 16, 0, 0);                 \
    }                                                                          \
  }

#define PV_BLOAD(KS, BR)                                                       \
  {                                                                            \
    BR[0] = *(const bf16x8*)(Bp0 + (KS) * 16384);                              \
    BR[1] = *(const bf16x8*)(Bp1 + (KS) * 16384);                              \
    BR[2] = *(const bf16x8*)(Bp2 + (KS) * 16384);                              \
    BR[3] = *(const bf16x8*)(Bp3 + (KS) * 16384);                              \
  }

#define PV_ITER(KS, BUSE, BFILL)                                               \
  {                                                                            \
    if ((KS) < 70)       { if (w == 0) WAITVM(12); else WAITVM(10); }          \
    else if ((KS) == 70) { if (w == 0) WAITVM(10); else WAITVM(8); }           \
    else                 WAITVM(4);                                            \
    __builtin_amdgcn_sched_barrier(0);                                         \
    __builtin_amdgcn_s_barrier();                                              \
    bf16x8 af[9];                                                              \
    _Pragma("unroll")                                                          \
    for (int mi = 0; mi < 9; ++mi)                                             \
      af[mi] = *(const bf16x8*)&As[cur][(mi * 16 + lr) * 32 + sw];             \
    __builtin_amdgcn_s_setprio(1);                                             \
    _Pragma("unroll")                                                          \
    for (int mi = 0; mi < 9; ++mi)                                             \
      _Pragma("unroll")                                                        \
      for (int nj = 0; nj < 4; ++nj)                                           \
        acc[mi][nj] = __builtin_amdgcn_mfma_f32_16x16x32_bf16(                 \
            af[mi], BUSE[nj], acc[mi][nj], 0, 0, 0);                           \
    __builtin_amdgcn_s_setprio(0);                                             \
    __builtin_amdgcn_s_barrier();                                              \
    if ((KS) + 2 < 72) PV_BLOAD((KS) + 2, BFILL);                              \
    if ((KS) + 3 < 72) PVA_STAGE((KS) + 3, cur);                               \
    cur = (cur == 2) ? 0 : cur + 1;                                            \
  }

  bf16x8 bA[4], bB[4];
  PVA_STAGE(0, 0);
  PVA_STAGE(1, 1);
  PVA_STAGE(2, 2);
  PV_BLOAD(0, bA);
  PV_BLOAD(1, bB);
  int cur = 0;
  for (int ks = 0; ks < 72; ks += 2) {
    PV_ITER(ks, bA, bA);
    PV_ITER(ks + 1, bB, bB);
  }
#undef PV_ITER
#undef PV_BLOAD
#undef PVA_STAGE

  const float* lv = linv + (size_t)cb * 2304 + row0;
  short* Db = Dp + (size_t)bb * 2304 * 512;
  const int col = w * 64 + lr * 4;                 // permuted position
  const int coff = (col >> 5) * 4096 + (col & 31); // tiled col part
#pragma unroll
  for (int mi = 0; mi < 9; ++mi) {
#pragma unroll
    for (int r = 0; r < 4; ++r) {
      const int row = mi * 16 + lg * 4 + r;
      const float s = lv[row];
      const int R = row0 + row;
      s16x4 o = { f2bf(acc[mi][0][r] * s), f2bf(acc[mi][1][r] * s),
                  f2bf(acc[mi][2][r] * s), f2bf(acc[mi][3][r] * s) };
      *(s16x4*)(Db + (R >> 7) * 65536 + coff + (R & 127) * 32) = o;
    }
  }
}

// ---------------- launcher ---------------------------------------------------
extern "C" void kernel_launch(void* const* d_in, const int* in_sizes, int n_in,
                              void* d_out, int out_size, void* d_ws, size_t ws_size,
                              hipStream_t stream) {
  const float* x     = (const float*)d_in[0];
  const float* gamma = (const float*)d_in[1];
  const float* beta  = (const float*)d_in[2];
  const float* wq    = (const float*)d_in[3];
  const float* bq    = (const float*)d_in[4];
  const float* wk    = (const float*)d_in[5];
  // d_in[6] = bk: unused (per-row constant, cancels in softmax)
  const float* wv    = (const float*)d_in[7];
  const float* bv    = (const float*)d_in[8];
  const float* wo    = (const float*)d_in[9];
  const float* bo    = (const float*)d_in[10];

  char* ws = (char*)d_ws;
  float2* stats = (float2*)(ws + 0);
  short*  Wv    = (short*)(ws + 8192);
  short*  Wo    = (short*)(ws + 532480);
  short*  WkT   = (short*)(ws + 1056768);
  short*  WqT   = (short*)(ws + 1581056);
  short*  G     = (short*)(ws + 2105344);
  float*  g0    = (float*)(ws + 2629632);
  short*  yT    = (short*)(ws + 2631680);     //  36 MB  [B] K-chunk-tiled
  short*  zoT   = (short*)(ws + 40380416);    //  36 MB  z -> oT, tiled
  short*  vbuf  = (short*)(ws + 78129152);    //  36 MB  [B][72][32][16][32] tiled
  short*  Praw  = (short*)(ws + 115877888);   //  CH * 10,616,832 [b][18][2304][128]
  float*  out   = (float*)d_out;

  const size_t base = 115877888ull;
  const size_t per  = 10616832ull + 331776ull + 9216ull;  // Praw+Tsum+linv
  int CH = 16;
  if (ws_size < base + 16 * per) CH = (ws_size >= base + 8 * per) ? 8 : 4;
  float* Tsum = (float*)(ws + base + (size_t)CH * 10616832ull);
  float* linv = (float*)(ws + base + (size_t)CH * (10616832ull + 331776ull));

  const size_t sBN = (size_t)2304 * 512;

  prep_k<<<1024, 256, 0, stream>>>(wq, wk, wv, wo, Wv, Wo, WkT, WqT);
  g0_k<<<2, 256, 0, stream>>>(wk, bq, g0);
  gn_stats<<<512, 256, 0, stream>>>(x, stats);
  gn_norm_t<<<dim3(36, 8, 16), 256, 0, stream>>>(x, stats, gamma, beta, yT);
  // G[c'][c] = sum_o WkT[c'][o] * WqT[c][o]   (G stored tiled)
  gemm_k<2, false, false, false, true, 512, 512, 16><<<dim3(16, 1), 256, 0, stream>>>(
      WkT, 0, WqT, 0, G, 0, nullptr, nullptr, 512, 4, 0);
  // v[b][o][n] = sum_c Wv[o][c] * yT[b][n][c] + bv[o]  (vbuf-tiled store)
  gemm_k<3, true, true, true, false, 512, 512, 16><<<dim3(72, 16), 256, 0, stream>>>(
      Wv, 0, yT, sBN, vbuf, sBN, bv, nullptr, 2304, 4, 0);
  // z[b][i][c'] = sum_c yT[b][i][c] * G[c'][c] + g0[c']  (z stored tiled)
  gemm_k<0, false, true, true, true, 512, 512, 16><<<dim3(72, 16), 256, 0, stream>>>(
      yT, sBN, G, 0, zoT, sBN, g0, nullptr, 512, 18, 0);

  for (int b0 = 0; b0 < 16; b0 += CH) {
    const int n = (16 - b0 < CH) ? (16 - b0) : CH;
    gemm_s<<<dim3(324, n), 256, 0, stream>>>(zoT, yT, Praw, Tsum, b0);
    sum_k<<<(n * 2304 + 255) / 256, 256, 0, stream>>>(Tsum, linv, n * 2304);
    gemm_pv<<<dim3(16, n), 512, 0, stream>>>(Praw, linv, vbuf, zoT, b0);
  }
  // out[b][o][n] = sum_c Wo[o][c] * oT[b][n][c] + bo[o] + x[b][o][n]
  gemm_k<1, true, true, true, false, 512, 512, 16><<<dim3(72, 16), 256, 0, stream>>>(
      Wo, 0, zoT, sBN, out, (size_t)512 * 2304, bo, x, 2304, 4, 0);
}

// Round 13
// 415.429 us; speedup vs baseline: 1.4947x; 1.0253x over previous
//
#include <hip/hip_runtime.h>

#define DI __device__ __forceinline__

typedef __attribute__((ext_vector_type(8))) short bf16x8;
typedef __attribute__((ext_vector_type(4))) short s16x4;
typedef __attribute__((ext_vector_type(4))) float f32x4;

DI short f2bf(float f) {
  unsigned u = __builtin_bit_cast(unsigned, f);
  u += 0x7FFFu + ((u >> 16) & 1u);
  return (short)(u >> 16);
}

#define WAITVM(N) asm volatile("s_waitcnt vmcnt(" #N ")" ::: "memory")
#define AS1 __attribute__((address_space(1)))
#define AS3 __attribute__((address_space(3)))

// Within-64 column permutation used for packed epilogues:
//   position p holds true column c:  p = (c&~63) + (c&15)*4 + ((c>>4)&3)
// Applied consistently to {P cols, vbuf j} (PV contraction) and
// {Wo cols, oT cols} (output-GEMM contraction) -> cancels algebraically.
//
// R8: vbuf tiled [jb=72][cb=32][16][32] (1KB-contiguous loads).
// R9: all bf16 [n][512] intermediates K-chunk-tiled:
//   off(n,k) = (n>>7)*65536 + (k>>5)*4096 + (n&127)*32 + (k&31)
// R12: dispatch-linear XCD-batch grouping (FETCH 208->92MB, confirmed).
// R13: gemm_s -> 128x256 tile, 8 waves/512 thr. Halves barrier-pairs per
// output WITHOUT losing residency (72KB LDS -> 2 blocks = 16 waves/CU,
// vs R11's depth-4 which dropped a block). Staging -25%/output; uniform
// 3 loads/thread/stage -> clean vmcnt 6/3/0.

// ---------------- prep: weights -> bf16 (+ transposed Wk/Wq for G) ----------
__global__ __launch_bounds__(256) void prep_k(
    const float* __restrict__ wq, const float* __restrict__ wk,
    const float* __restrict__ wv, const float* __restrict__ wo,
    short* __restrict__ Wv, short* __restrict__ Wo,
    short* __restrict__ WkT, short* __restrict__ WqT) {
  const int i = blockIdx.x * 256 + threadIdx.x;  // 0..262143
  const float sc = 0.04419417382415922f;         // 1/sqrt(512)
  const int o = i >> 9, c = i & 511;
  Wv[(o >> 7) * 65536 + (c >> 5) * 4096 + (o & 127) * 32 + (c & 31)] = f2bf(wv[i]);
  const int cp = (c & ~63) | ((c & 15) << 2) | ((c >> 4) & 3);
  Wo[(o >> 7) * 65536 + (cp >> 5) * 4096 + (o & 127) * 32 + (cp & 31)] = f2bf(wo[i]);
  const int tr = c * 512 + o;
  WkT[tr] = f2bf(wk[i] * sc);   // scale folded into Wk side
  WqT[tr] = f2bf(wq[i]);
}

// ---------------- g0[c'] = s * sum_o wk[o][c'] * bq[o] ----------------------
__global__ __launch_bounds__(256) void g0_k(const float* __restrict__ wk,
                                            const float* __restrict__ bq,
                                            float* __restrict__ g0) {
  const int c = blockIdx.x * 256 + threadIdx.x;  // 0..511
  float acc = 0.f;
#pragma unroll 8
  for (int o = 0; o < 512; ++o) acc += wk[o * 512 + c] * bq[o];
  g0[c] = acc * 0.04419417382415922f;
}

// ---------------- GroupNorm pass 1: per (b,g) mean/rstd ---------------------
__global__ __launch_bounds__(256) void gn_stats(const float* __restrict__ x,
                                                float2* __restrict__ stats) {
  const int bg = blockIdx.x;
  const float4* xg = (const float4*)(x + (size_t)bg * 36864);
  float s = 0.f, q = 0.f;
  for (int i = threadIdx.x; i < 9216; i += 256) {
    float4 v = xg[i];
    s += v.x + v.y + v.z + v.w;
    q += v.x * v.x + v.y * v.y + v.z * v.z + v.w * v.w;
  }
#pragma unroll
  for (int d = 1; d < 64; d <<= 1) { s += __shfl_xor(s, d); q += __shfl_xor(q, d); }
  __shared__ float rs[4], rq[4];
  const int w = threadIdx.x >> 6;
  if ((threadIdx.x & 63) == 0) { rs[w] = s; rq[w] = q; }
  __syncthreads();
  if (threadIdx.x == 0) {
    float S = rs[0] + rs[1] + rs[2] + rs[3];
    float Q = rq[0] + rq[1] + rq[2] + rq[3];
    float mean = S * (1.f / 36864.f);
    float var  = Q * (1.f / 36864.f) - mean * mean;
    float2 o; o.x = mean; o.y = rsqrtf(var + 1e-5f);
    stats[bg] = o;
  }
}

// ---------------- GroupNorm pass 2: normalize + transpose -> yT bf16 --------
__global__ __launch_bounds__(256) void gn_norm_t(
    const float* __restrict__ x, const float2* __restrict__ stats,
    const float* __restrict__ gamma, const float* __restrict__ beta,
    short* __restrict__ yT) {
  __shared__ float ts[64][68];
  const int n0 = blockIdx.x * 64, c0 = blockIdx.y * 64, b = blockIdx.z;
  const int t = threadIdx.x;
  {
    const int cw = t >> 4;
    const int n4 = (t & 15) * 4;
    const float* xb = x + ((size_t)b * 512 + c0) * 2304 + n0;
#pragma unroll
    for (int r4 = 0; r4 < 4; ++r4) {
      const int c = cw + r4 * 16;
      float4 v = *(const float4*)(xb + (size_t)c * 2304 + n4);
      *(float4*)&ts[c][n4] = v;
    }
  }
  __syncthreads();
  {
    const int c4 = t & 15;
    const int nw = t >> 4;
    const int cg = c0 + c4 * 4;
    const float2 ms = stats[b * 32 + (cg >> 4)];
    const float4 gm = *(const float4*)(gamma + cg);
    const float4 bt = *(const float4*)(beta + cg);
    const float a0 = ms.y * gm.x, a1 = ms.y * gm.y, a2 = ms.y * gm.z, a3 = ms.y * gm.w;
    const float d0 = bt.x - ms.x * a0, d1 = bt.y - ms.x * a1,
                d2 = bt.z - ms.x * a2, d3 = bt.w - ms.x * a3;
#pragma unroll
    for (int it = 0; it < 4; ++it) {
      const int no = nw + it * 16;
      const int n = n0 + no;
      const float v0 = ts[c4 * 4 + 0][no], v1 = ts[c4 * 4 + 1][no];
      const float v2 = ts[c4 * 4 + 2][no], v3 = ts[c4 * 4 + 3][no];
      s16x4 o = { f2bf(v0 * a0 + d0), f2bf(v1 * a1 + d1),
                  f2bf(v2 * a2 + d2), f2bf(v3 * a3 + d3) };
      *(s16x4*)(yT + (size_t)b * 2304 * 512 + (n >> 7) * 65536 +
                (cg >> 5) * 4096 + (n & 127) * 32 + (cg & 31)) = o;
    }
  }
}

// ---------------- Generic bf16 MFMA GEMM (depth-3 ring, R12 form) -----------
// D[M][N] = A[M][K] * Bt[N][K]^T, 128x128 tile, BK=32.
template <int EPI, bool BIASROW, bool AT, bool BT, bool DT, int LDA, int LDB,
          int KSTEPS>
__global__ __launch_bounds__(256) void gemm_k(
    const short* __restrict__ A, size_t sA,
    const short* __restrict__ Bt, size_t sB,
    void* __restrict__ Dp, size_t sD,
    const float* __restrict__ bias, const float* __restrict__ resid,
    int N, int tilesM, int boff) {
  __shared__ short As[3][128 * 32];
  __shared__ short Bs[3][128 * 32];
  int bx, cb;
  if (gridDim.y == 16) {
    const int gx = gridDim.x;                       // 72
    const int id = blockIdx.y * gx + blockIdx.x;    // dispatch-linear
    const int xcd = id & 7, r = id >> 3;            // r in [0, 2*gx)
    cb = xcd * 2 + (r >= gx ? 1 : 0);               // this XCD's 2 batches
    bx = (r >= gx) ? r - gx : r;
  } else {
    bx = blockIdx.x;
    bx = (bx & 7) * (int)(gridDim.x >> 3) + (bx >> 3);
    cb = blockIdx.y;
  }
  const int ba = cb, bb = cb + boff;
  const int tm = bx % tilesM, tn = bx / tilesM;
  const int row0 = tm * 128, col0 = tn * 128;
  const int tid = threadIdx.x, lane = tid & 63, w = tid >> 6;
  const int lr = lane & 15, lg = lane >> 4;
  const short* Ab = A + (size_t)ba * sA;
  const short* Bb = Bt + (size_t)bb * sB;
  f32x4 acc[4][4];
  const f32x4 zero = {0.f, 0.f, 0.f, 0.f};
#pragma unroll
  for (int i = 0; i < 4; ++i)
#pragma unroll
    for (int j = 0; j < 4; ++j) acc[i][j] = zero;
  const int wrow = (w & 1) * 64, wcol = (w >> 1) * 64;
  const int sw = (lg ^ ((lr >> 1) & 3)) * 8;

#define GK_STAGE(KS, BUF)                                                      \
  {                                                                            \
    _Pragma("unroll")                                                          \
    for (int j = 0; j < 2; ++j) {                                              \
      const int g = (w * 2 + j) * 64 + lane;                                   \
      const int sub8 = ((g & 3) ^ ((g >> 3) & 3)) * 8;                         \
      const short* ga = AT ? (Ab + (size_t)row0 * 512 + (KS) * 4096 +          \
                              (g >> 2) * 32 + sub8)                            \
                           : (Ab + (size_t)(row0 + (g >> 2)) * LDA +           \
                              (KS) * 32 + sub8);                               \
      const short* gb = BT ? (Bb + (size_t)col0 * 512 + (KS) * 4096 +          \
                              (g >> 2) * 32 + sub8)                            \
                           : (Bb + (size_t)(col0 + (g >> 2)) * LDB +           \
                              (KS) * 32 + sub8);                               \
      __builtin_amdgcn_global_load_lds(                                        \
          (AS1 void*)ga, (AS3 void*)&As[BUF][(w * 2 + j) * 512], 16, 0, 0);    \
      __builtin_amdgcn_global_load_lds(                                        \
          (AS1 void*)gb, (AS3 void*)&Bs[BUF][(w * 2 + j) * 512], 16, 0, 0);    \
    }                                                                          \
  }

  GK_STAGE(0, 0);
  GK_STAGE(1, 1);
  GK_STAGE(2, 2);
  int cur = 0;
  for (int ks = 0; ks < KSTEPS; ++ks) {
    if (ks + 2 < KSTEPS)      WAITVM(8);
    else if (ks + 1 < KSTEPS) WAITVM(4);
    else                      WAITVM(0);
    __builtin_amdgcn_sched_barrier(0);
    __builtin_amdgcn_s_barrier();
    bf16x8 af[4], bfr[4];
#pragma unroll
    for (int mi = 0; mi < 4; ++mi)
      af[mi] = *(const bf16x8*)&As[cur][(wrow + mi * 16 + lr) * 32 + sw];
#pragma unroll
    for (int nj = 0; nj < 4; ++nj)
      bfr[nj] = *(const bf16x8*)&Bs[cur][(wcol + nj * 16 + lr) * 32 + sw];
    __builtin_amdgcn_s_setprio(1);
#pragma unroll
    for (int mi = 0; mi < 4; ++mi)
#pragma unroll
      for (int nj = 0; nj < 4; ++nj)
        acc[mi][nj] = __builtin_amdgcn_mfma_f32_16x16x32_bf16(af[mi], bfr[nj], acc[mi][nj], 0, 0, 0);
    __builtin_amdgcn_s_setprio(0);
    __builtin_amdgcn_s_barrier();
    if (ks + 3 < KSTEPS) { GK_STAGE(ks + 3, cur) }
    cur = (cur == 2) ? 0 : cur + 1;
  }
#undef GK_STAGE

  const size_t bD = (size_t)bb * sD;
  if (EPI == 3) {
    const int colpos = col0 + wcol + lr * 4;
    const int jb = colpos >> 5, j5 = colpos & 31;
#pragma unroll
    for (int mi = 0; mi < 4; ++mi) {
#pragma unroll
      for (int r = 0; r < 4; ++r) {
        const int row = row0 + wrow + mi * 16 + lg * 4 + r;
        const float bv = bias[row];
        const int off = (jb * 32 + (row >> 4)) * 512 + ((row & 15) << 5) + j5;
        s16x4 o = { f2bf(acc[mi][0][r] + bv), f2bf(acc[mi][1][r] + bv),
                    f2bf(acc[mi][2][r] + bv), f2bf(acc[mi][3][r] + bv) };
        *(s16x4*)&((short*)Dp)[bD + off] = o;
      }
    }
  } else {
#pragma unroll
    for (int mi = 0; mi < 4; ++mi) {
#pragma unroll
      for (int nj = 0; nj < 4; ++nj) {
        const int col = col0 + wcol + nj * 16 + lr;
#pragma unroll
        for (int r = 0; r < 4; ++r) {
          const int row = row0 + wrow + mi * 16 + lg * 4 + r;
          float v = acc[mi][nj][r];
          if (EPI != 2) v += (BIASROW ? bias[row] : bias[col]);
          if (EPI == 1) {
            const size_t idx = bD + (size_t)row * N + col;
            ((float*)Dp)[idx] = v + resid[idx];
          } else {
            const size_t idx = bD + (DT
                ? (size_t)((row >> 7) * 65536 + (col >> 5) * 4096 +
                           (row & 127) * 32 + (col & 31))
                : (size_t)row * N + col);
            ((short*)Dp)[idx] = f2bf(v);
          }
        }
      }
    }
  }
}

// ---------------- S-GEMM: 128x256 tile, 8 waves (R13) -----------------------
// S[i][j] = z_i . y_j ; P = exp(S - 30) stored bf16, column-PERMUTED within
// 64-blocks (matches vbuf's j-permutation), packed 8B stores.
// Wave w: 64x64 subtile at (wrow=(w&1)*64, wcol=(w>>1)*64 of 256 cols).
// Depth-3 ring, uniform 3 loads/thread/stage (1 A + 2 B) -> vmcnt 6/3/0.
// 72KB LDS -> 2 resident blocks = 16 waves/CU; barrier-pairs per output
// halved vs 128x128. Grid 162x16 (div 8), 2-batch/XCD grouping, tm fastest.
__global__ __launch_bounds__(512, 4) void gemm_s(
    const short* __restrict__ z, const short* __restrict__ yT,
    short* __restrict__ Praw, float* __restrict__ Tsum, int b0) {
  __shared__ short As[3][128 * 32];   // 3 x 8 KB
  __shared__ short Bs[3][256 * 32];   // 3 x 16 KB
  int tm, tn, cb;
  if (gridDim.y == 16) {
    const int id = blockIdx.y * 162 + blockIdx.x;   // dispatch-linear
    const int xcd = id & 7, r = id >> 3;            // r in [0,324)
    cb = xcd * 2 + (r >= 162 ? 1 : 0);
    const int rr = (r >= 162) ? r - 162 : r;
    tm = rr % 18; tn = rr / 18;                     // tn in [0,9), tm fastest
  } else {
    cb = blockIdx.y; tm = blockIdx.x % 18; tn = blockIdx.x / 18;
  }
  const int b = b0 + cb;
  const int row0 = tm * 128, col0 = tn * 256;
  const int tid = threadIdx.x, lane = tid & 63, w = tid >> 6;  // 8 waves
  const int lr = lane & 15, lg = lane >> 4;
  const short* Ab = z + (size_t)b * 2304 * 512;
  const short* Bb = yT + (size_t)b * 2304 * 512;
  f32x4 acc[4][4];
  const f32x4 zero = {0.f, 0.f, 0.f, 0.f};
#pragma unroll
  for (int i = 0; i < 4; ++i)
#pragma unroll
    for (int j = 0; j < 4; ++j) acc[i][j] = zero;
  const int wrow = (w & 1) * 64, wcol = (w >> 1) * 64;  // wcol in {0,64,128,192}
  const int sw = (lg ^ ((lr >> 1) & 3)) * 8;

  // stage: A chunk g=tid (512 chunks); B chunks g=tid and g=tid+512 (1024).
  // sub8 identical for tid and tid+512 (512>>3 = 64 ≡ 0 mod 4).
#define GS_STAGE(KS, BUF)                                                      \
  {                                                                            \
    const int sub8 = ((tid & 3) ^ ((tid >> 3) & 3)) * 8;                       \
    const short* ga = Ab + (size_t)row0 * 512 + (KS) * 4096 +                  \
                      (tid >> 2) * 32 + sub8;                                  \
    __builtin_amdgcn_global_load_lds(                                          \
        (AS1 void*)ga, (AS3 void*)&As[BUF][w * 512], 16, 0, 0);                \
    const short* gb0 = Bb + (size_t)col0 * 512 + (KS) * 4096 +                 \
                       (tid >> 2) * 32 + sub8;                                 \
    __builtin_amdgcn_global_load_lds(                                          \
        (AS1 void*)gb0, (AS3 void*)&Bs[BUF][w * 512], 16, 0, 0);               \
    const short* gb1 = Bb + (size_t)col0 * 512 + 65536 + (KS) * 4096 +         \
                       (tid >> 2) * 32 + sub8;                                 \
    __builtin_amdgcn_global_load_lds(                                          \
        (AS1 void*)gb1, (AS3 void*)&Bs[BUF][4096 + w * 512], 16, 0, 0);        \
  }

  GS_STAGE(0, 0);
  GS_STAGE(1, 1);
  GS_STAGE(2, 2);
  int cur = 0;
  for (int ks = 0; ks < 16; ++ks) {
    if (ks < 14)      WAITVM(6);   // 3 stages out (9 loads): oldest landed
    else if (ks < 15) WAITVM(3);
    else              WAITVM(0);
    __builtin_amdgcn_sched_barrier(0);
    __builtin_amdgcn_s_barrier();
    bf16x8 af[4], bfr[4];
#pragma unroll
    for (int mi = 0; mi < 4; ++mi)
      af[mi] = *(const bf16x8*)&As[cur][(wrow + mi * 16 + lr) * 32 + sw];
#pragma unroll
    for (int nj = 0; nj < 4; ++nj)
      bfr[nj] = *(const bf16x8*)&Bs[cur][(wcol + nj * 16 + lr) * 32 + sw];
    __builtin_amdgcn_s_setprio(1);
#pragma unroll
    for (int mi = 0; mi < 4; ++mi)
#pragma unroll
      for (int nj = 0; nj < 4; ++nj)
        acc[mi][nj] = __builtin_amdgcn_mfma_f32_16x16x32_bf16(af[mi], bfr[nj], acc[mi][nj], 0, 0, 0);
    __builtin_amdgcn_s_setprio(0);
    __builtin_amdgcn_s_barrier();
    if (ks + 3 < 16) { GS_STAGE(ks + 3, cur) }
    cur = (cur == 2) ? 0 : cur + 1;
  }
#undef GS_STAGE
  // epilogue: exp(acc-30), per-row partial sums, packed bf16 P store.
  // 128-col P tile index and 64-half from wcol.
  const int tn128 = tn * 2 + (wcol >> 7);
  const int c64 = wcol & 64;
  short* Pp = Praw + ((size_t)(cb * 18 + tn128) * 2304 + row0) * 128 + c64;
  float* Ts = Tsum + ((size_t)cb * 2304 + row0) * 36 + tn128 * 2 + (c64 >> 6);
#pragma unroll
  for (int mi = 0; mi < 4; ++mi) {
#pragma unroll
    for (int r = 0; r < 4; ++r) {
      const int row = wrow + mi * 16 + lg * 4 + r;
      float pv0 = __expf(acc[mi][0][r] - 30.f);
      float pv1 = __expf(acc[mi][1][r] - 30.f);
      float pv2 = __expf(acc[mi][2][r] - 30.f);
      float pv3 = __expf(acc[mi][3][r] - 30.f);
      float sum = pv0 + pv1 + pv2 + pv3;
#pragma unroll
      for (int d = 1; d < 16; d <<= 1) sum += __shfl_xor(sum, d);
      if (lr == 0) Ts[(size_t)row * 36] = sum;
      s16x4 o = { f2bf(pv0), f2bf(pv1), f2bf(pv2), f2bf(pv3) };
      *(s16x4*)(Pp + (size_t)row * 128 + lr * 4) = o;
    }
  }
}

// ---------------- linv[row] = 1 / sum_t Tsum[row][t] ------------------------
__global__ __launch_bounds__(256) void sum_k(
    const float* __restrict__ Tsum, float* __restrict__ linv, int nrows) {
  const int r = blockIdx.x * 256 + threadIdx.x;
  if (r >= nrows) return;
  const float* ts = Tsum + (size_t)r * 36;
  float l = 0.f;
#pragma unroll
  for (int t = 0; t < 36; ++t) l += ts[t];
  linv[r] = 1.f / l;
}

// ---------------- PV GEMM (R9 form: R5 structure + tiled-V loads) -----------
// oT[i][c] = linv[i] * sum_j Praw[i][j] * v[c][j]  (j,c in permuted space)
// 16 tm-tiles x 16 batches = 256 blocks = exactly 1 block/CU. 8 waves; wave w
// owns c-slice [64w,64w+64). A (P) staged in LDS depth-3 ring; V loads from
// tiled vbuf (1KB contiguous). oT stored K-chunk-tiled for the out-GEMM.
__global__ __launch_bounds__(512) void gemm_pv(
    const short* __restrict__ Praw, const float* __restrict__ linv,
    const short* __restrict__ vsrc, short* __restrict__ Dp, int b0) {
  __shared__ short As[3][144 * 32];   // 3 x 9 KB
  int tm, cb;
  if (gridDim.y == 16) {
    const int id = blockIdx.y * 16 + blockIdx.x;   // 256 blocks
    const int xcd = id & 7, r = id >> 3;           // r in [0,32)
    cb = xcd * 2 + (r >= 16 ? 1 : 0);
    tm = r & 15;
  } else {
    cb = blockIdx.y; tm = blockIdx.x;
  }
  const int bb = b0 + cb;
  const int row0 = tm * 144;
  const int tid = threadIdx.x, lane = tid & 63, w = tid >> 6;  // 8 waves
  const int lr = lane & 15, lg = lane >> 4;
  const short* Ab = Praw + (size_t)cb * 18 * 2304 * 128;
  const short* Bb = vsrc + (size_t)bb * 512 * 2304;
  const short* Bp0 = Bb + (w * 4 + 0) * 512 + lr * 32 + lg * 8;
  const short* Bp1 = Bb + (w * 4 + 1) * 512 + lr * 32 + lg * 8;
  const short* Bp2 = Bb + (w * 4 + 2) * 512 + lr * 32 + lg * 8;
  const short* Bp3 = Bb + (w * 4 + 3) * 512 + lr * 32 + lg * 8;
  f32x4 acc[9][4];
  const f32x4 zero = {0.f, 0.f, 0.f, 0.f};
#pragma unroll
  for (int i = 0; i < 9; ++i)
#pragma unroll
    for (int j = 0; j < 4; ++j) acc[i][j] = zero;
  const int sw = (lg ^ ((lr >> 1) & 3)) * 8;

#define PVA_STAGE(KS, BUF)                                                     \
  {                                                                            \
    const int kt = (KS) >> 2, k32 = ((KS) & 3) * 32;                           \
    {                                                                          \
      const int g = tid;                                                       \
      const short* ga = Ab + ((size_t)kt * 2304 + row0 + (g >> 2)) * 128 +     \
                        k32 + (((g & 3) ^ ((g >> 3) & 3)) * 8);                \
      __builtin_amdgcn_global_load_lds(                                        \
          (AS1 void*)ga, (AS3 void*)&As[BUF][w * 512], 16, 0, 0);              \
    }                                                                          \
    if (w == 0) {                                                              \
      const int g = 512 + tid;                                                 \
      const short* ga = Ab + ((size_t)kt * 2304 + row0 + (g >> 2)) * 128 +     \
                        k32 + (((g & 3) ^ ((g >> 3) & 3)) * 8);                \
      __builtin_amdgcn_global_load_lds(                                        \
          (AS1 void*)ga, (AS3 void*)&As[BUF][4096], 16, 0, 0);                 \
    }                                                                          \
  }

#define PV_BLOAD(KS, BR)                                                       \
  {                                                                            \
    BR[0] = *(const bf16x8*)(Bp0 + (KS) * 16384);                              \
    BR[1] = *(const bf16x8*)(Bp1 + (KS) * 16384);                              \
    BR[2] = *(const bf16x8*)(Bp2 + (KS) * 16384);                              \
    BR[3] = *(const bf16x8*)(Bp3 + (KS) * 16384);                              \
  }

#define PV_ITER(KS, BUSE, BFILL)                                               \
  {                                                                            \
    if ((KS) < 70)       { if (w == 0) WAITVM(12); else WAITVM(10); }          \
    else if ((KS) == 70) { if (w == 0) WAITVM(10); else WAITVM(8); }           \
    else                 WAITVM(4);                                            \
    __builtin_amdgcn_sched_barrier(0);                                         \
    __builtin_amdgcn_s_barrier();                                              \
    bf16x8 af[9];                                                              \
    _Pragma("unroll")                                                          \
    for (int mi = 0; mi < 9; ++mi)                                             \
      af[mi] = *(const bf16x8*)&As[cur][(mi * 16 + lr) * 32 + sw];             \
    __builtin_amdgcn_s_setprio(1);                                             \
    _Pragma("unroll")                                                          \
    for (int mi = 0; mi < 9; ++mi)                                             \
      _Pragma("unroll")                                                        \
      for (int nj = 0; nj < 4; ++nj)                                           \
        acc[mi][nj] = __builtin_amdgcn_mfma_f32_16x16x32_bf16(                 \
            af[mi], BUSE[nj], acc[mi][nj], 0, 0, 0);                           \
    __builtin_amdgcn_s_setprio(0);                                             \
    __builtin_amdgcn_s_barrier();                                              \
    if ((KS) + 2 < 72) PV_BLOAD((KS) + 2, BFILL);                              \
    if ((KS) + 3 < 72) PVA_STAGE((KS) + 3, cur);                               \
    cur = (cur == 2) ? 0 : cur + 1;                                            \
  }

  bf16x8 bA[4], bB[4];
  PVA_STAGE(0, 0);
  PVA_STAGE(1, 1);
  PVA_STAGE(2, 2);
  PV_BLOAD(0, bA);
  PV_BLOAD(1, bB);
  int cur = 0;
  for (int ks = 0; ks < 72; ks += 2) {
    PV_ITER(ks, bA, bA);
    PV_ITER(ks + 1, bB, bB);
  }
#undef PV_ITER
#undef PV_BLOAD
#undef PVA_STAGE

  const float* lv = linv + (size_t)cb * 2304 + row0;
  short* Db = Dp + (size_t)bb * 2304 * 512;
  const int col = w * 64 + lr * 4;                 // permuted position
  const int coff = (col >> 5) * 4096 + (col & 31); // tiled col part
#pragma unroll
  for (int mi = 0; mi < 9; ++mi) {
#pragma unroll
    for (int r = 0; r < 4; ++r) {
      const int row = mi * 16 + lg * 4 + r;
      const float s = lv[row];
      const int R = row0 + row;
      s16x4 o = { f2bf(acc[mi][0][r] * s), f2bf(acc[mi][1][r] * s),
                  f2bf(acc[mi][2][r] * s), f2bf(acc[mi][3][r] * s) };
      *(s16x4*)(Db + (R >> 7) * 65536 + coff + (R & 127) * 32) = o;
    }
  }
}

// ---------------- launcher ---------------------------------------------------
extern "C" void kernel_launch(void* const* d_in, const int* in_sizes, int n_in,
                              void* d_out, int out_size, void* d_ws, size_t ws_size,
                              hipStream_t stream) {
  const float* x     = (const float*)d_in[0];
  const float* gamma = (const float*)d_in[1];
  const float* beta  = (const float*)d_in[2];
  const float* wq    = (const float*)d_in[3];
  const float* bq    = (const float*)d_in[4];
  const float* wk    = (const float*)d_in[5];
  // d_in[6] = bk: unused (per-row constant, cancels in softmax)
  const float* wv    = (const float*)d_in[7];
  const float* bv    = (const float*)d_in[8];
  const float* wo    = (const float*)d_in[9];
  const float* bo    = (const float*)d_in[10];

  char* ws = (char*)d_ws;
  float2* stats = (float2*)(ws + 0);
  short*  Wv    = (short*)(ws + 8192);
  short*  Wo    = (short*)(ws + 532480);
  short*  WkT   = (short*)(ws + 1056768);
  short*  WqT   = (short*)(ws + 1581056);
  short*  G     = (short*)(ws + 2105344);
  float*  g0    = (float*)(ws + 2629632);
  short*  yT    = (short*)(ws + 2631680);     //  36 MB  [B] K-chunk-tiled
  short*  zoT   = (short*)(ws + 40380416);    //  36 MB  z -> oT, tiled
  short*  vbuf  = (short*)(ws + 78129152);    //  36 MB  [B][72][32][16][32] tiled
  short*  Praw  = (short*)(ws + 115877888);   //  CH * 10,616,832 [b][18][2304][128]
  float*  out   = (float*)d_out;

  const size_t base = 115877888ull;
  const size_t per  = 10616832ull + 331776ull + 9216ull;  // Praw+Tsum+linv
  int CH = 16;
  if (ws_size < base + 16 * per) CH = (ws_size >= base + 8 * per) ? 8 : 4;
  float* Tsum = (float*)(ws + base + (size_t)CH * 10616832ull);
  float* linv = (float*)(ws + base + (size_t)CH * (10616832ull + 331776ull));

  const size_t sBN = (size_t)2304 * 512;

  prep_k<<<1024, 256, 0, stream>>>(wq, wk, wv, wo, Wv, Wo, WkT, WqT);
  g0_k<<<2, 256, 0, stream>>>(wk, bq, g0);
  gn_stats<<<512, 256, 0, stream>>>(x, stats);
  gn_norm_t<<<dim3(36, 8, 16), 256, 0, stream>>>(x, stats, gamma, beta, yT);
  // G[c'][c] = sum_o WkT[c'][o] * WqT[c][o]   (G stored tiled)
  gemm_k<2, false, false, false, true, 512, 512, 16><<<dim3(16, 1), 256, 0, stream>>>(
      WkT, 0, WqT, 0, G, 0, nullptr, nullptr, 512, 4, 0);
  // v[b][o][n] = sum_c Wv[o][c] * yT[b][n][c] + bv[o]  (vbuf-tiled store)
  gemm_k<3, true, true, true, false, 512, 512, 16><<<dim3(72, 16), 256, 0, stream>>>(
      Wv, 0, yT, sBN, vbuf, sBN, bv, nullptr, 2304, 4, 0);
  // z[b][i][c'] = sum_c yT[b][i][c] * G[c'][c] + g0[c']  (z stored tiled)
  gemm_k<0, false, true, true, true, 512, 512, 16><<<dim3(72, 16), 256, 0, stream>>>(
      yT, sBN, G, 0, zoT, sBN, g0, nullptr, 512, 18, 0);

  for (int b0 = 0; b0 < 16; b0 += CH) {
    const int n = (16 - b0 < CH) ? (16 - b0) : CH;
    gemm_s<<<dim3(162, n), 512, 0, stream>>>(zoT, yT, Praw, Tsum, b0);
    sum_k<<<(n * 2304 + 255) / 256, 256, 0, stream>>>(Tsum, linv, n * 2304);
    gemm_pv<<<dim3(16, n), 512, 0, stream>>>(Praw, linv, vbuf, zoT, b0);
  }
  // out[b][o][n] = sum_c Wo[o][c] * oT[b][n][c] + bo[o] + x[b][o][n]
  gemm_k<1, true, true, true, false, 512, 512, 16><<<dim3(72, 16), 256, 0, stream>>>(
      Wo, 0, zoT, sBN, out, (size_t)512 * 2304, bo, x, 2304, 4, 0);
}